// Round 4
// baseline (154.560 us; speedup 1.0000x reference)
//
#include <hip/hip_runtime.h>
#include <hip/hip_bf16.h>

#define B 64
#define L 100
#define WDIM 300
#define PDIM 50
#define DIM 350
#define NROWS 144           // padded rows per batch (row r -> l' = r-3)
#define NK0 11              // 352 / 32 k-chunks
#define NCOMB 384
#define NSHIFT 7
#define NKK 77              // 11 k0 * 7 s
#define N_CANDS 20
#define N_POSS 10
#define NB_PER_CAND 64
#define TDIM 128
#define EDIM 128
#define CTX_DIM 768
#define EN_HID1 896
#define EN_DIM 512
#define NEG_INF_F 1.0e10f

typedef __attribute__((ext_vector_type(8))) short bf16x8;
typedef __attribute__((ext_vector_type(4))) float f32x4;
typedef __attribute__((ext_vector_type(16))) float f32x16;

__device__ __forceinline__ void gload_lds16(const __hip_bfloat16* g,
                                            __hip_bfloat16* l) {
  __builtin_amdgcn_global_load_lds(
      (const __attribute__((address_space(1))) unsigned int*)(g),
      (__attribute__((address_space(3))) unsigned int*)(l), 16, 0, 0);
}

// ---------------------------------------------------------------------------
// cast three f32 tables to bf16 (type_emb, rel_emb, rel_weight)
__global__ __launch_bounds__(256) void k_cast3(
    const float* __restrict__ s1, int n1, const float* __restrict__ s2, int n2,
    const float* __restrict__ s3, int n3, __hip_bfloat16* __restrict__ d1,
    __hip_bfloat16* __restrict__ d2, __hip_bfloat16* __restrict__ d3) {
  int nt = n1 + n2 + n3;
  for (int i = blockIdx.x * 256 + threadIdx.x; i < nt; i += gridDim.x * 256) {
    if (i < n1) d1[i] = __float2bfloat16(s1[i]);
    else if (i < n1 + n2) d2[i - n1] = __float2bfloat16(s2[i - n1]);
    else d3[i - n1 - n2] = __float2bfloat16(s3[i - n1 - n2]);
  }
}

// ---------------------------------------------------------------------------
// P1: bricked input Xbr[b][k0][row 144][k 32] bf16; row r -> l' = r-3.
__global__ __launch_bounds__(256) void k_build_xbr(
    const int* __restrict__ tokens, const int* __restrict__ pos,
    const float* __restrict__ word_embs, const float* __restrict__ pos_emb,
    __hip_bfloat16* __restrict__ Xbr) {
  int b = blockIdx.x;
  int r0 = blockIdx.y * 8;
  for (int r = r0; r < r0 + 8; ++r) {
    int lp = r - 3;
    __hip_bfloat16* base = Xbr + (size_t)b * (NK0 * NROWS * 32);
    if (lp >= 0 && lp < L) {
      int tok = tokens[b * L + lp];
      int pp = pos[b * L + lp] + 100;
      const float* wrow = word_embs + (size_t)tok * WDIM;
      const float* prow = pos_emb + (size_t)pp * PDIM;
      for (int d = threadIdx.x; d < 352; d += 256) {
        float v = (d < WDIM) ? wrow[d] : (d < DIM) ? prow[d - WDIM] : 0.f;
        base[((size_t)(d >> 5) * NROWS + r) * 32 + (d & 31)] =
            __float2bfloat16(v);
      }
    } else {
      for (int d = threadIdx.x; d < 352; d += 256)
        base[((size_t)(d >> 5) * NROWS + r) * 32 + (d & 31)] =
            __float2bfloat16(0.f);
    }
  }
}

// ---------------------------------------------------------------------------
// P2: conv weight bricks Wbr[ncg 3][kk 77][col 128][k 32] bf16.
__global__ __launch_bounds__(128) void k_prep_wbr(
    const float* __restrict__ w3, const float* __restrict__ w5,
    const float* __restrict__ w7, __hip_bfloat16* __restrict__ Wbr) {
  int kkb = blockIdx.x;  // 0..76
  int ncg = blockIdx.y;
  int k0 = kkb / NSHIFT, s = kkb - NSHIFT * k0;
  int col = threadIdx.x;  // 0..127, f = col within conv group ncg
  const float* w = (ncg == 0) ? w3 : (ncg == 1) ? w5 : w7;
  int fs = (ncg == 0) ? 3 : (ncg == 1) ? 5 : 7;
  int dl = (ncg == 0) ? s - 2 : (ncg == 1) ? s - 1 : s;
  bool valid = (dl >= 0 && dl < fs);
  __hip_bfloat16* dst = Wbr + (((size_t)ncg * NKK + kkb) * 128 + col) * 32;
  for (int k = 0; k < 32; ++k) {
    int d = k0 * 32 + k;
    float v = (valid && d < DIM) ? w[((size_t)col * fs + dl) * DIM + d] : 0.f;
    dst[k] = __float2bfloat16(v);
  }
}

// ---------------------------------------------------------------------------
// P3: scorer/noise W1 bricks: W1br[which][sub 16][k0 56][col 32][k 16] bf16.
__global__ __launch_bounds__(256) void k_prep_w1br(
    const float* __restrict__ sW1, const float* __restrict__ nW1,
    __hip_bfloat16* __restrict__ W1br) {
  int which = blockIdx.x;
  int sub = blockIdx.y;
  const float* src = which ? nW1 : sW1;
  __hip_bfloat16* dst = W1br + (size_t)which * (16 * 56 * 512);
  for (int idx = threadIdx.x; idx < 32 * EN_HID1; idx += 256) {
    int col = idx / EN_HID1, k = idx - col * EN_HID1;
    float v = src[(size_t)k * EN_DIM + sub * 32 + col];
    dst[((size_t)(sub * 56 + (k >> 4)) * 32 + col) * 16 + (k & 15)] =
        __float2bfloat16(v);
  }
}

// ---------------------------------------------------------------------------
// K2: candidate embeddings -> bf16 (bf16 gather tables).
__global__ __launch_bounds__(128) void k_cand(
    const int* __restrict__ nb_types, const int* __restrict__ nb_n_types,
    const int* __restrict__ nb_rs, const __hip_bfloat16* __restrict__ typeb,
    const __hip_bfloat16* __restrict__ relb,
    const __hip_bfloat16* __restrict__ relwb,
    __hip_bfloat16* __restrict__ candb) {
  int c = blockIdx.x, d = threadIdx.x;
  __shared__ int srs[NB_PER_CAND];
  __shared__ float sinv[NB_PER_CAND];
  __shared__ int sty[NB_PER_CAND * 4];
  for (int i = d; i < NB_PER_CAND * 4; i += 128)
    sty[i] = nb_types[c * NB_PER_CAND * 4 + i];
  if (d < NB_PER_CAND) {
    srs[d] = nb_rs[c * NB_PER_CAND + d];
    sinv[d] = 1.f / (float)nb_n_types[c * NB_PER_CAND + d];
  }
  __syncthreads();
  float accS = 0.f, accR = 0.f;
#pragma unroll 4
  for (int j = 0; j < NB_PER_CAND; ++j) {
    accR += __bfloat162float(relb[srs[j] * EDIM + d]);
    float s4 = 0.f;
#pragma unroll
    for (int k = 0; k < 4; ++k)
      s4 += __bfloat162float(typeb[sty[j * 4 + k] * TDIM + d]);
    accS = fmaf(s4, sinv[j], accS);
  }
  __shared__ float sS[TDIM];
  sS[d] = accS;
  __syncthreads();
  float dot = accR;
#pragma unroll 4
  for (int k = 0; k < TDIM; ++k)
    dot = fmaf(sS[k], __bfloat162float(relwb[k * EDIM + d]), dot);
  candb[(size_t)c * EDIM + d] = __float2bfloat16(fmaxf(dot, 0.f));
}

// ---------------------------------------------------------------------------
// K3: conv implicit-GEMM. Block (b, ncg): tile 128 rows x 128 cols,
// 4 waves (2m x 2n), each 64x64 via 4x4 of 16x16x32 MFMA. LDS-staged,
// double-buffered; one A-stage per k0 serves all 7 shifts (read at +s rows).
__global__ __launch_bounds__(256) void k_conv_mfma(
    const __hip_bfloat16* __restrict__ Xbr,
    const __hip_bfloat16* __restrict__ Wbr, const int* __restrict__ pos,
    const float* __restrict__ masks, const float* __restrict__ b3,
    const float* __restrict__ b5, const float* __restrict__ b7,
    __hip_bfloat16* __restrict__ ctxb) {
  int b = blockIdx.x;
  int ncg = blockIdx.y;
  int tid = threadIdx.x;
  int wv = tid >> 6, ln = tid & 63;
  int wm = wv >> 1, wn = wv & 1;
  int l15 = ln & 15, kg = ln >> 4;

  __shared__ __align__(16) __hip_bfloat16 Ab[2][NROWS * 32];  // 9216B each
  __shared__ __align__(16) __hip_bfloat16 Bb[2][128 * 32];    // 8192B each
  __shared__ float sml[128], smr[128];
  __shared__ float redl[2][128], redr[2][128];

  for (int l = tid; l < 128; l += 256) {
    float mlv = 0.f, mrv = 0.f;
    if (l < L) {
      int p = pos[b * L + l];
      mlv = (p <= 0) ? 1.f : 0.f;
      mrv = (p >= 0) ? masks[b * L + l] : 0.f;
    }
    sml[l] = mlv;
    smr[l] = mrv;
  }

  const __hip_bfloat16* Xb = Xbr + (size_t)b * (NK0 * NROWS * 32);
  const __hip_bfloat16* Wb = Wbr + (size_t)ncg * (NKK * 128 * 32);

  // prologue: stage A(k0=0), B(kk=0)
  for (int seg = wv; seg < 9; seg += 4)
    gload_lds16(Xb + seg * 512 + ln * 8, &Ab[0][seg * 512 + ln * 8]);
  for (int seg = wv; seg < 8; seg += 4)
    gload_lds16(Wb + seg * 512 + ln * 8, &Bb[0][seg * 512 + ln * 8]);
  __syncthreads();

  f32x4 acc[4][4];
#pragma unroll
  for (int i = 0; i < 4; ++i)
#pragma unroll
    for (int j = 0; j < 4; ++j) acc[i][j] = (f32x4){0.f, 0.f, 0.f, 0.f};

  int ab = 0, bbuf = 0, k0 = 0, s = 0;
  for (int kk = 0; kk < NKK; ++kk) {
    if (kk < NKK - 1) {
      const __hip_bfloat16* bsrc = Wb + (size_t)(kk + 1) * 4096;
      for (int seg = wv; seg < 8; seg += 4)
        gload_lds16(bsrc + seg * 512 + ln * 8,
                    &Bb[bbuf ^ 1][seg * 512 + ln * 8]);
      if (s == 6) {
        const __hip_bfloat16* asrc = Xb + (size_t)(k0 + 1) * 4608;
        for (int seg = wv; seg < 9; seg += 4)
          gload_lds16(asrc + seg * 512 + ln * 8,
                      &Ab[ab ^ 1][seg * 512 + ln * 8]);
      }
    }
    int rbase = wm * 64 + l15 + s;
    bf16x8 af[4], bfr[4];
#pragma unroll
    for (int i = 0; i < 4; ++i)
      af[i] = *(const bf16x8*)&Ab[ab][(rbase + 16 * i) * 32 + kg * 8];
#pragma unroll
    for (int j = 0; j < 4; ++j)
      bfr[j] = *(const bf16x8*)&Bb[bbuf][(wn * 64 + 16 * j + l15) * 32 + kg * 8];
#pragma unroll
    for (int i = 0; i < 4; ++i)
#pragma unroll
      for (int j = 0; j < 4; ++j)
        acc[i][j] =
            __builtin_amdgcn_mfma_f32_16x16x32_bf16(af[i], bfr[j], acc[i][j],
                                                    0, 0, 0);
    __syncthreads();
    bbuf ^= 1;
    if (++s == 7) {
      s = 0;
      ++k0;
      ab ^= 1;
    }
  }

  const float* barr = (ncg == 0) ? b3 : (ncg == 1) ? b5 : b7;
#pragma unroll
  for (int j = 0; j < 4; ++j) {
    int fcol = wn * 64 + 16 * j + l15;  // 0..127
    float bias = barr[fcol];
    float mpl = -NEG_INF_F, mpr = -NEG_INF_F;
#pragma unroll
    for (int i = 0; i < 4; ++i) {
#pragma unroll
      for (int r = 0; r < 4; ++r) {
        int row = wm * 64 + 16 * i + 4 * kg + r;
        float cva = fmaxf(acc[i][j][r] + bias, 0.f);
        float ml = sml[row], mr = smr[row];
        mpl = fmaxf(mpl, cva * ml - (1.f - ml) * NEG_INF_F);
        mpr = fmaxf(mpr, cva * mr - (1.f - mr) * NEG_INF_F);
      }
    }
    mpl = fmaxf(mpl, __shfl_xor(mpl, 16));
    mpl = fmaxf(mpl, __shfl_xor(mpl, 32));
    mpr = fmaxf(mpr, __shfl_xor(mpr, 16));
    mpr = fmaxf(mpr, __shfl_xor(mpr, 32));
    if (ln < 16) {
      redl[wm][wn * 64 + 16 * j + ln] = mpl;
      redr[wm][wn * 64 + 16 * j + ln] = mpr;
    }
  }
  __syncthreads();
  if (tid < 128) {
    float vl = fmaxf(redl[0][tid], redl[1][tid]);
    float vr = fmaxf(redr[0][tid], redr[1][tid]);
    ctxb[(size_t)b * CTX_DIM + ncg * 128 + tid] = __float2bfloat16(vl);
    ctxb[(size_t)b * CTX_DIM + 384 + ncg * 128 + tid] = __float2bfloat16(vr);
  }
}

// ---------------------------------------------------------------------------
// K5/K7: scorer & noise MLP GEMM. A (32 rows x 896) staged in padded LDS,
// B from bricked W1 (coalesced direct loads). Epilogue folds relu * W2 and
// reduces across the wave's 32 n-cols.
__global__ __launch_bounds__(256) void k_mlp_gemm(
    const __hip_bfloat16* __restrict__ ctxb,
    const __hip_bfloat16* __restrict__ tail,
    const __hip_bfloat16* __restrict__ W1br_all, int which,
    const float* __restrict__ b1, const float* __restrict__ W2,
    float* __restrict__ outP, int mdiv, int Mtot) {
  int mt = blockIdx.x;
  int w = threadIdx.x >> 6;
  int sub = blockIdx.y * 4 + w;
  int lane = threadIdx.x & 63;
  int lrow = lane & 31, kg2 = lane >> 5;
  __shared__ __align__(16) __hip_bfloat16 As[32][904];

  {
    int row = threadIdx.x >> 3, seg = threadIdx.x & 7;
    int m = mt * 32 + row;
    int bb = (mdiv == 1) ? m : m / 20;
#pragma unroll
    for (int q = 0; q < 14; ++q) {
      int k = seg * 112 + q * 8;
      bf16x8 v;
      if (k < CTX_DIM)
        v = *(const bf16x8*)&ctxb[(size_t)bb * CTX_DIM + k];
      else
        v = *(const bf16x8*)&tail[(size_t)m * EDIM + (k - CTX_DIM)];
      *(bf16x8*)&As[row][k] = v;
    }
  }
  __syncthreads();

  const __hip_bfloat16* W1b = W1br_all + (size_t)which * (16 * 56 * 512);
  f32x16 acc = {};
#pragma unroll 4
  for (int k0 = 0; k0 < 56; ++k0) {
    bf16x8 av = *(const bf16x8*)&As[lrow][k0 * 16 + kg2 * 8];
    bf16x8 bv = *(const bf16x8*)&W1b[((size_t)sub * 56 + k0) * 512 +
                                     lrow * 16 + kg2 * 8];
    acc = __builtin_amdgcn_mfma_f32_32x32x16_bf16(av, bv, acc, 0, 0, 0);
  }
  int n = sub * 32 + lrow;
  float b1n = b1[n], w2n = W2[n];
#pragma unroll
  for (int r = 0; r < 16; ++r) {
    float v = fmaxf(acc[r] + b1n, 0.f) * w2n;
#pragma unroll
    for (int off = 16; off; off >>= 1) v += __shfl_xor(v, off);
    if (lrow == 0) {
      int mm = mt * 32 + (r & 3) + 8 * (r >> 2) + 4 * kg2;
      outP[(size_t)sub * Mtot + mm] = v;
    }
  }
}

// ---------------------------------------------------------------------------
// K6: finish scores, softmax(10), e = sum p*cand -> bf16.
__global__ __launch_bounds__(128) void k_softmax_e(
    const float* __restrict__ part, const __hip_bfloat16* __restrict__ candb,
    const int* __restrict__ real_n_poss, const float* __restrict__ sb2,
    float* __restrict__ out, __hip_bfloat16* __restrict__ eb) {
  int b = blockIdx.x, t = threadIdx.x;
  __shared__ float ssc[N_CANDS];
  __shared__ float sp[N_POSS];
  if (t < N_CANDS) {
    int m = b * N_CANDS + t;
    float s = sb2[0];
#pragma unroll
    for (int i = 0; i < 16; ++i) s += part[(size_t)i * (B * N_CANDS) + m];
    if (t < N_POSS && (t + 1) > real_n_poss[b]) s = -NEG_INF_F;
    ssc[t] = s;
    out[m] = s;
  }
  __syncthreads();
  if (t == 0) {
    float mx = -INFINITY;
    for (int c = 0; c < N_POSS; ++c) mx = fmaxf(mx, ssc[c]);
    float ssum = 0.f;
    float pe[N_POSS];
    for (int c = 0; c < N_POSS; ++c) {
      pe[c] = expf(ssc[c] - mx);
      ssum += pe[c];
    }
    float inv = 1.f / ssum;
    for (int c = 0; c < N_POSS; ++c) sp[c] = pe[c] * inv;
  }
  __syncthreads();
  float ev = 0.f;
#pragma unroll
  for (int c = 0; c < N_POSS; ++c)
    ev = fmaf(sp[c],
              __bfloat162float(candb[(size_t)(b * N_CANDS + c) * EDIM + t]),
              ev);
  eb[(size_t)b * EDIM + t] = __float2bfloat16(ev);
}

__global__ __launch_bounds__(64) void k_noise_fin(
    const float* __restrict__ part_n, const float* __restrict__ nb2,
    float* __restrict__ out) {
  int b = threadIdx.x;
  float s = nb2[0];
#pragma unroll
  for (int i = 0; i < 16; ++i) s += part_n[(size_t)i * B + b];
  out[B * N_CANDS + b] = s;
}

// ---------------------------------------------------------------------------
extern "C" void kernel_launch(void* const* d_in, const int* in_sizes, int n_in,
                              void* d_out, int out_size, void* d_ws,
                              size_t ws_size, hipStream_t stream) {
  const int* tokens = (const int*)d_in[0];
  const int* pos = (const int*)d_in[1];
  const float* masks = (const float*)d_in[2];
  const int* nb_types = (const int*)d_in[3];
  const int* nb_n_types = (const int*)d_in[5];
  const int* nb_rs = (const int*)d_in[6];
  const int* real_n_poss = (const int*)d_in[8];
  const float* word_embs = (const float*)d_in[10];
  const float* pos_emb = (const float*)d_in[11];
  const float* type_emb = (const float*)d_in[12];
  const float* rel_emb = (const float*)d_in[13];
  const float* rel_weight = (const float*)d_in[14];
  const float* w3 = (const float*)d_in[15];
  const float* b3 = (const float*)d_in[16];
  const float* w5 = (const float*)d_in[17];
  const float* b5 = (const float*)d_in[18];
  const float* w7 = (const float*)d_in[19];
  const float* b7 = (const float*)d_in[20];
  const float* sW1 = (const float*)d_in[21];
  const float* sb1 = (const float*)d_in[22];
  const float* sW2 = (const float*)d_in[23];
  const float* sb2 = (const float*)d_in[24];
  const float* nW1 = (const float*)d_in[25];
  const float* nb1 = (const float*)d_in[26];
  const float* nW2 = (const float*)d_in[27];
  const float* nb2 = (const float*)d_in[28];

  __hip_bfloat16* Xbr = (__hip_bfloat16*)d_ws;            // 3,244,032
  __hip_bfloat16* Wbr = Xbr + (size_t)3244032;            //   946,176
  __hip_bfloat16* W1br = Wbr + (size_t)946176;            //   917,504
  __hip_bfloat16* ctxb = W1br + (size_t)917504;           //    49,152
  __hip_bfloat16* candb = ctxb + (size_t)49152;           //   163,840
  __hip_bfloat16* eb = candb + (size_t)163840;            //     8,192
  __hip_bfloat16* typeb = eb + (size_t)8192;              //   640,000
  __hip_bfloat16* relb = typeb + (size_t)640000;          //    64,000
  __hip_bfloat16* relwb = relb + (size_t)64000;           //    16,384
  float* part = (float*)(relwb + (size_t)16384);          //    20,480 f32
  float* part_n = part + (size_t)16 * B * N_CANDS;        //     1,024 f32
  float* out = (float*)d_out;

  hipLaunchKernelGGL(k_cast3, dim3(720), dim3(256), 0, stream, type_emb,
                     5000 * TDIM, rel_emb, 500 * EDIM, rel_weight, TDIM * EDIM,
                     typeb, relb, relwb);
  hipLaunchKernelGGL(k_build_xbr, dim3(B, NROWS / 8), dim3(256), 0, stream,
                     tokens, pos, word_embs, pos_emb, Xbr);
  hipLaunchKernelGGL(k_prep_wbr, dim3(NKK, 3), dim3(128), 0, stream, w3, w5,
                     w7, Wbr);
  hipLaunchKernelGGL(k_prep_w1br, dim3(2, 16), dim3(256), 0, stream, sW1, nW1,
                     W1br);
  hipLaunchKernelGGL(k_cand, dim3(B * N_CANDS), dim3(128), 0, stream, nb_types,
                     nb_n_types, nb_rs, typeb, relb, relwb, candb);
  hipLaunchKernelGGL(k_conv_mfma, dim3(B, 3), dim3(256), 0, stream, Xbr, Wbr,
                     pos, masks, b3, b5, b7, ctxb);
  hipLaunchKernelGGL(k_mlp_gemm, dim3(40, 4), dim3(256), 0, stream, ctxb,
                     candb, W1br, 0, sb1, sW2, part, 20, B * N_CANDS);
  hipLaunchKernelGGL(k_softmax_e, dim3(B), dim3(128), 0, stream, part, candb,
                     real_n_poss, sb2, out, eb);
  hipLaunchKernelGGL(k_mlp_gemm, dim3(2, 4), dim3(256), 0, stream, ctxb, eb,
                     W1br, 1, nb1, nW2, part_n, 1, B);
  hipLaunchKernelGGL(k_noise_fin, dim3(1), dim3(64), 0, stream, part_n, nb2,
                     out);
}

// Round 5
// 128.545 us; speedup vs baseline: 1.2024x; 1.2024x over previous
//
#include <hip/hip_runtime.h>
#include <hip/hip_bf16.h>

#define B 64
#define L 100
#define WDIM 300
#define PDIM 50
#define DIM 350
#define NK0 11              // 352/32 k-chunks
#define BRICK_ROWS 144      // rows per (b,k0) brick; row r -> l' = r-3
#define NSHIFT 7
#define NKK 77              // 11 k0 * 7 shifts
#define N_CANDS 20
#define N_POSS 10
#define NB_PER_CAND 64
#define TDIM 128
#define EDIM 128
#define CTX_DIM 768
#define EN_HID1 896
#define EN_DIM 512
#define NEG_INF_F 1.0e10f

typedef __attribute__((ext_vector_type(8))) short bf16x8;
typedef __attribute__((ext_vector_type(4))) float f32x4;
typedef __attribute__((ext_vector_type(16))) float f32x16;

__device__ __forceinline__ void gload_lds16(const __hip_bfloat16* g,
                                            __hip_bfloat16* l) {
  __builtin_amdgcn_global_load_lds(
      (const __attribute__((address_space(1))) unsigned int*)(g),
      (__attribute__((address_space(3))) unsigned int*)(l), 16, 0, 0);
}

__device__ __forceinline__ bf16x8 cvt8(float4 a, float4 b) {
  union { bf16x8 v; __hip_bfloat16 h[8]; } u;
  u.h[0] = __float2bfloat16(a.x); u.h[1] = __float2bfloat16(a.y);
  u.h[2] = __float2bfloat16(a.z); u.h[3] = __float2bfloat16(a.w);
  u.h[4] = __float2bfloat16(b.x); u.h[5] = __float2bfloat16(b.y);
  u.h[6] = __float2bfloat16(b.z); u.h[7] = __float2bfloat16(b.w);
  return u.v;
}

// ---------------------------------------------------------------------------
// K_PREP (fused): [0,704) cast tables to bf16; [704,752) init ctxpool=-1e10;
// [752,1904) build Xbr bricks; [1904,2135) build Wbr; [2135,2167) build W1br.
__global__ __launch_bounds__(256) void k_prep(
    const float* __restrict__ type_emb, const float* __restrict__ rel_emb,
    const float* __restrict__ rel_weight, __hip_bfloat16* __restrict__ typeb,
    __hip_bfloat16* __restrict__ relb, __hip_bfloat16* __restrict__ relwb,
    const int* __restrict__ tokens, const int* __restrict__ pos,
    const float* __restrict__ word_embs, const float* __restrict__ pos_emb,
    __hip_bfloat16* __restrict__ Xbr, const float* __restrict__ w3,
    const float* __restrict__ w5, const float* __restrict__ w7,
    __hip_bfloat16* __restrict__ Wbr, const float* __restrict__ sW1,
    const float* __restrict__ nW1, __hip_bfloat16* __restrict__ W1br,
    float* __restrict__ ctxpool) {
  int blk = blockIdx.x, tid = threadIdx.x;
  if (blk < 704) {
    const int n1 = 5000 * TDIM, n2 = 500 * EDIM, n3 = TDIM * EDIM;
    int i0 = blk * 1024 + tid;
#pragma unroll
    for (int q = 0; q < 4; ++q) {
      int i = i0 + q * 256;
      if (i < n1) typeb[i] = __float2bfloat16(type_emb[i]);
      else if (i < n1 + n2) relb[i - n1] = __float2bfloat16(rel_emb[i - n1]);
      else if (i < n1 + n2 + n3)
        relwb[i - n1 - n2] = __float2bfloat16(rel_weight[i - n1 - n2]);
    }
  } else if (blk < 752) {
    int i0 = (blk - 704) * 1024 + tid * 4;
#pragma unroll
    for (int q = 0; q < 4; ++q) ctxpool[i0 + q] = -NEG_INF_F;
  } else if (blk < 1904) {
    int idx = blk - 752;
    int b = idx / 18, r0 = (idx % 18) * 8;
    __hip_bfloat16* base = Xbr + (size_t)b * (NK0 * BRICK_ROWS * 32);
    for (int r = r0; r < r0 + 8; ++r) {
      int lp = r - 3;
      if (lp >= 0 && lp < L) {
        int tok = tokens[b * L + lp];
        int pp = pos[b * L + lp] + 100;
        const float* wrow = word_embs + (size_t)tok * WDIM;
        const float* prow = pos_emb + (size_t)pp * PDIM;
        for (int d = tid; d < 352; d += 256) {
          float v = (d < WDIM) ? wrow[d] : (d < DIM) ? prow[d - WDIM] : 0.f;
          base[((size_t)(d >> 5) * BRICK_ROWS + r) * 32 + (d & 31)] =
              __float2bfloat16(v);
        }
      } else {
        for (int d = tid; d < 352; d += 256)
          base[((size_t)(d >> 5) * BRICK_ROWS + r) * 32 + (d & 31)] =
              __float2bfloat16(0.f);
      }
    }
  } else if (blk < 2135) {
    int idx = blk - 1904;  // 0..230
    int ncg = idx / NKK, kkb = idx % NKK;
    if (tid < 128) {
      int k0 = kkb / NSHIFT, s = kkb - NSHIFT * k0;
      int col = tid;
      const float* w = (ncg == 0) ? w3 : (ncg == 1) ? w5 : w7;
      int fs = (ncg == 0) ? 3 : (ncg == 1) ? 5 : 7;
      int dl = (ncg == 0) ? s - 2 : (ncg == 1) ? s - 1 : s;
      bool valid = (dl >= 0 && dl < fs);
      __hip_bfloat16* dst = Wbr + (((size_t)ncg * NKK + kkb) * 128 + col) * 32;
      for (int k = 0; k < 32; ++k) {
        int d = k0 * 32 + k;
        float v =
            (valid && d < DIM) ? w[((size_t)col * fs + dl) * DIM + d] : 0.f;
        dst[k] = __float2bfloat16(v);
      }
    }
  } else {
    int idx = blk - 2135;  // 0..31
    int which = idx >> 4, sub = idx & 15;
    const float* src = which ? nW1 : sW1;
    __hip_bfloat16* dst = W1br + (size_t)which * (16 * 56 * 512);
    for (int i = tid; i < 32 * EN_HID1; i += 256) {
      int col = i / EN_HID1, k = i - col * EN_HID1;
      float v = src[(size_t)k * EN_DIM + sub * 32 + col];
      dst[((size_t)(sub * 56 + (k >> 4)) * 32 + col) * 16 + (k & 15)] =
          __float2bfloat16(v);
    }
  }
}

// ---------------------------------------------------------------------------
// K_CAND: 256 threads; neighbor loop split across 2 groups of 128 lanes,
// then split matvec. One block per candidate.
__global__ __launch_bounds__(256) void k_cand(
    const int* __restrict__ nb_types, const int* __restrict__ nb_n_types,
    const int* __restrict__ nb_rs, const __hip_bfloat16* __restrict__ typeb,
    const __hip_bfloat16* __restrict__ relb,
    const __hip_bfloat16* __restrict__ relwb,
    __hip_bfloat16* __restrict__ candb) {
  int c = blockIdx.x, tid = threadIdx.x;
  int g = tid >> 7, d = tid & 127;
  __shared__ int sty[NB_PER_CAND * 4];
  __shared__ int srs[NB_PER_CAND];
  __shared__ float sinv[NB_PER_CAND];
  __shared__ float pS[2][128], pR[2][128], sS[128];
  sty[tid] = nb_types[c * NB_PER_CAND * 4 + tid];
  if (tid < NB_PER_CAND) {
    srs[tid] = nb_rs[c * NB_PER_CAND + tid];
    sinv[tid] = 1.f / (float)nb_n_types[c * NB_PER_CAND + tid];
  }
  __syncthreads();
  float accS = 0.f, accR = 0.f;
#pragma unroll 4
  for (int j2 = 0; j2 < 32; ++j2) {
    int j = g * 32 + j2;
    accR += __bfloat162float(relb[srs[j] * EDIM + d]);
    float s4 = 0.f;
#pragma unroll
    for (int k = 0; k < 4; ++k)
      s4 += __bfloat162float(typeb[sty[j * 4 + k] * TDIM + d]);
    accS = fmaf(s4, sinv[j], accS);
  }
  pS[g][d] = accS;
  pR[g][d] = accR;
  __syncthreads();
  if (tid < 128) sS[d] = pS[0][d] + pS[1][d];
  __syncthreads();
  float dotp = (g == 0) ? (pR[0][d] + pR[1][d]) : 0.f;
#pragma unroll 4
  for (int k2 = 0; k2 < 64; ++k2) {
    int k = g * 64 + k2;
    dotp = fmaf(sS[k], __bfloat162float(relwb[k * EDIM + d]), dotp);
  }
  pS[g][d] = dotp;
  __syncthreads();
  if (tid < 128)
    candb[(size_t)c * EDIM + d] =
        __float2bfloat16(fmaxf(pS[0][d] + pS[1][d], 0.f));
}

// ---------------------------------------------------------------------------
// K_CONV: implicit-GEMM, 64x64 tiles, grid (B, 2 mt, 6 nt) = 768 blocks
// (3/CU). 4 waves as 2m x 2n, each 32x32 via 2x2 of 16x16x32 MFMA. LDS
// double-buffered via global_load_lds; one A-stage per k0 serves 7 shifts.
// Masked max-pool accumulated cross-block via atomicMax(float-as-int).
__global__ __launch_bounds__(256) void k_conv_mfma(
    const __hip_bfloat16* __restrict__ Xbr,
    const __hip_bfloat16* __restrict__ Wbr, const int* __restrict__ pos,
    const float* __restrict__ masks, const float* __restrict__ b3,
    const float* __restrict__ b5, const float* __restrict__ b7,
    float* __restrict__ ctxpool) {
  int b = blockIdx.x;
  int mt = blockIdx.y;           // 0..1: output rows mt*64..+63
  int nt = blockIdx.z;           // 0..5
  int ncg = nt >> 1, nh = nt & 1;
  int tid = threadIdx.x;
  int wv = tid >> 6, ln = tid & 63;
  int wm = wv >> 1, wn = wv & 1;
  int l15 = ln & 15, kg = ln >> 4;

  __shared__ __align__(16) __hip_bfloat16 Asb[2][72 * 32];
  __shared__ __align__(16) __hip_bfloat16 Bsb[2][64 * 32];
  __shared__ float sml[64], smr[64];

  for (int i = tid; i < 64; i += 256) {
    int l = mt * 64 + i;
    float mlv = 0.f, mrv = 0.f;
    if (l < L) {
      int p = pos[b * L + l];
      mlv = (p <= 0) ? 1.f : 0.f;
      mrv = (p >= 0) ? masks[b * L + l] : 0.f;
    }
    sml[i] = mlv;
    smr[i] = mrv;
  }

  const __hip_bfloat16* XB =
      Xbr + (size_t)b * (NK0 * BRICK_ROWS * 32) + (size_t)mt * 64 * 32;
  const __hip_bfloat16* WB =
      Wbr + ((size_t)ncg * NKK * 128 + (size_t)nh * 64) * 32;

  // prologue: stage A(k0=0) 72 rows (9x512), B(kk=0) 64 rows (4x512)
  for (int seg = wv; seg < 9; seg += 4)
    gload_lds16(XB + seg * 512 + ln * 8, &Asb[0][seg * 512 + ln * 8]);
  gload_lds16(WB + wv * 512 + ln * 8, &Bsb[0][wv * 512 + ln * 8]);
  __syncthreads();

  f32x4 acc[2][2];
#pragma unroll
  for (int i = 0; i < 2; ++i)
#pragma unroll
    for (int j = 0; j < 2; ++j) acc[i][j] = (f32x4){0.f, 0.f, 0.f, 0.f};

  int ab = 0, bb = 0, k0 = 0, s = 0;
  for (int kk = 0; kk < NKK; ++kk) {
    if (kk < NKK - 1) {
      const __hip_bfloat16* bsrc = WB + (size_t)(kk + 1) * 4096;
      gload_lds16(bsrc + wv * 512 + ln * 8, &Bsb[bb ^ 1][wv * 512 + ln * 8]);
      if (s == 6) {
        const __hip_bfloat16* asrc = XB + (size_t)(k0 + 1) * (BRICK_ROWS * 32);
        for (int seg = wv; seg < 9; seg += 4)
          gload_lds16(asrc + seg * 512 + ln * 8,
                      &Asb[ab ^ 1][seg * 512 + ln * 8]);
      }
    }
    int rbase = wm * 32 + l15 + s;
    bf16x8 af0 = *(const bf16x8*)&Asb[ab][rbase * 32 + kg * 8];
    bf16x8 af1 = *(const bf16x8*)&Asb[ab][(rbase + 16) * 32 + kg * 8];
    bf16x8 bf0 = *(const bf16x8*)&Bsb[bb][(wn * 32 + l15) * 32 + kg * 8];
    bf16x8 bf1 = *(const bf16x8*)&Bsb[bb][(wn * 32 + 16 + l15) * 32 + kg * 8];
    acc[0][0] = __builtin_amdgcn_mfma_f32_16x16x32_bf16(af0, bf0, acc[0][0], 0, 0, 0);
    acc[0][1] = __builtin_amdgcn_mfma_f32_16x16x32_bf16(af0, bf1, acc[0][1], 0, 0, 0);
    acc[1][0] = __builtin_amdgcn_mfma_f32_16x16x32_bf16(af1, bf0, acc[1][0], 0, 0, 0);
    acc[1][1] = __builtin_amdgcn_mfma_f32_16x16x32_bf16(af1, bf1, acc[1][1], 0, 0, 0);
    __syncthreads();
    bb ^= 1;
    if (++s == 7) {
      s = 0;
      ++k0;
      ab ^= 1;
    }
  }

  const float* barr = (ncg == 0) ? b3 : (ncg == 1) ? b5 : b7;
#pragma unroll
  for (int j = 0; j < 2; ++j) {
    int fcol = nh * 64 + wn * 32 + 16 * j + l15;  // 0..127 within ncg
    float bias = barr[fcol];
    float mpl = -NEG_INF_F, mpr = -NEG_INF_F;
#pragma unroll
    for (int i = 0; i < 2; ++i) {
#pragma unroll
      for (int r = 0; r < 4; ++r) {
        int rl = wm * 32 + 16 * i + 4 * kg + r;
        float cva = fmaxf(acc[i][j][r] + bias, 0.f);
        float ml = sml[rl], mr = smr[rl];
        mpl = fmaxf(mpl, cva * ml - (1.f - ml) * NEG_INF_F);
        mpr = fmaxf(mpr, cva * mr - (1.f - mr) * NEG_INF_F);
      }
    }
    mpl = fmaxf(mpl, __shfl_xor(mpl, 16));
    mpl = fmaxf(mpl, __shfl_xor(mpl, 32));
    mpr = fmaxf(mpr, __shfl_xor(mpr, 16));
    mpr = fmaxf(mpr, __shfl_xor(mpr, 32));
    if (ln < 16) {
      // values are either >=0 or exactly -1e10, so int-bit ordering is exact
      atomicMax((int*)&ctxpool[(size_t)b * CTX_DIM + ncg * 128 + fcol],
                __float_as_int(mpl));
      atomicMax((int*)&ctxpool[(size_t)b * CTX_DIM + 384 + ncg * 128 + fcol],
                __float_as_int(mpr));
    }
  }
}

// ---------------------------------------------------------------------------
// K_MLP: scorer & noise MLP GEMM. A (32 rows x 896) staged in LDS with f32
// ctx converted to bf16 on the fly; B from bricked W1. Epilogue folds
// relu * W2 and reduces across the wave's 32 n-cols into partials.
__global__ __launch_bounds__(256) void k_mlp_gemm(
    const float* __restrict__ ctxp, const __hip_bfloat16* __restrict__ tail,
    const __hip_bfloat16* __restrict__ W1br_all, int which,
    const float* __restrict__ b1, const float* __restrict__ W2,
    float* __restrict__ outP, int mdiv, int Mtot) {
  int mt = blockIdx.x;
  int w = threadIdx.x >> 6;
  int sub = blockIdx.y * 4 + w;
  int lane = threadIdx.x & 63;
  int lrow = lane & 31, kg2 = lane >> 5;
  __shared__ __align__(16) __hip_bfloat16 As[32][904];

  {
    int row = threadIdx.x >> 3, seg = threadIdx.x & 7;
    int m = mt * 32 + row;
    int bb = (mdiv == 1) ? m : m / 20;
    const float* cp = ctxp + (size_t)bb * CTX_DIM;
#pragma unroll
    for (int q = 0; q < 14; ++q) {
      int k = seg * 112 + q * 8;
      bf16x8 v;
      if (k < CTX_DIM) {
        float4 f0 = *(const float4*)(cp + k);
        float4 f1 = *(const float4*)(cp + k + 4);
        v = cvt8(f0, f1);
      } else {
        v = *(const bf16x8*)&tail[(size_t)m * EDIM + (k - CTX_DIM)];
      }
      *(bf16x8*)&As[row][k] = v;
    }
  }
  __syncthreads();

  const __hip_bfloat16* W1b = W1br_all + (size_t)which * (16 * 56 * 512);
  f32x16 acc = {};
#pragma unroll 4
  for (int k0 = 0; k0 < 56; ++k0) {
    bf16x8 av = *(const bf16x8*)&As[lrow][k0 * 16 + kg2 * 8];
    bf16x8 bv = *(const bf16x8*)&W1b[((size_t)sub * 56 + k0) * 512 +
                                     lrow * 16 + kg2 * 8];
    acc = __builtin_amdgcn_mfma_f32_32x32x16_bf16(av, bv, acc, 0, 0, 0);
  }
  int n = sub * 32 + lrow;
  float b1n = b1[n], w2n = W2[n];
#pragma unroll
  for (int r = 0; r < 16; ++r) {
    float v = fmaxf(acc[r] + b1n, 0.f) * w2n;
#pragma unroll
    for (int off = 16; off; off >>= 1) v += __shfl_xor(v, off);
    if (lrow == 0) {
      int mm = mt * 32 + (r & 3) + 8 * (r >> 2) + 4 * kg2;
      outP[(size_t)sub * Mtot + mm] = v;
    }
  }
}

// ---------------------------------------------------------------------------
// K_SOFTMAX_E: finish scores, softmax(10), e = sum p*cand -> bf16.
__global__ __launch_bounds__(128) void k_softmax_e(
    const float* __restrict__ part, const __hip_bfloat16* __restrict__ candb,
    const int* __restrict__ real_n_poss, const float* __restrict__ sb2,
    float* __restrict__ out, __hip_bfloat16* __restrict__ eb) {
  int b = blockIdx.x, t = threadIdx.x;
  __shared__ float ssc[N_CANDS];
  __shared__ float sp[N_POSS];
  if (t < N_CANDS) {
    int m = b * N_CANDS + t;
    float s = sb2[0];
#pragma unroll
    for (int i = 0; i < 16; ++i) s += part[(size_t)i * (B * N_CANDS) + m];
    if (t < N_POSS && (t + 1) > real_n_poss[b]) s = -NEG_INF_F;
    ssc[t] = s;
    out[m] = s;
  }
  __syncthreads();
  if (t == 0) {
    float mx = -INFINITY;
    for (int c = 0; c < N_POSS; ++c) mx = fmaxf(mx, ssc[c]);
    float ssum = 0.f;
    float pe[N_POSS];
    for (int c = 0; c < N_POSS; ++c) {
      pe[c] = expf(ssc[c] - mx);
      ssum += pe[c];
    }
    float inv = 1.f / ssum;
    for (int c = 0; c < N_POSS; ++c) sp[c] = pe[c] * inv;
  }
  __syncthreads();
  float ev = 0.f;
#pragma unroll
  for (int c = 0; c < N_POSS; ++c)
    ev = fmaf(sp[c],
              __bfloat162float(candb[(size_t)(b * N_CANDS + c) * EDIM + t]),
              ev);
  eb[(size_t)b * EDIM + t] = __float2bfloat16(ev);
}

__global__ __launch_bounds__(64) void k_noise_fin(
    const float* __restrict__ part_n, const float* __restrict__ nb2,
    float* __restrict__ out) {
  int b = threadIdx.x;
  float s = nb2[0];
#pragma unroll
  for (int i = 0; i < 16; ++i) s += part_n[(size_t)i * B + b];
  out[B * N_CANDS + b] = s;
}

// ---------------------------------------------------------------------------
extern "C" void kernel_launch(void* const* d_in, const int* in_sizes, int n_in,
                              void* d_out, int out_size, void* d_ws,
                              size_t ws_size, hipStream_t stream) {
  const int* tokens = (const int*)d_in[0];
  const int* pos = (const int*)d_in[1];
  const float* masks = (const float*)d_in[2];
  const int* nb_types = (const int*)d_in[3];
  const int* nb_n_types = (const int*)d_in[5];
  const int* nb_rs = (const int*)d_in[6];
  const int* real_n_poss = (const int*)d_in[8];
  const float* word_embs = (const float*)d_in[10];
  const float* pos_emb = (const float*)d_in[11];
  const float* type_emb = (const float*)d_in[12];
  const float* rel_emb = (const float*)d_in[13];
  const float* rel_weight = (const float*)d_in[14];
  const float* w3 = (const float*)d_in[15];
  const float* b3 = (const float*)d_in[16];
  const float* w5 = (const float*)d_in[17];
  const float* b5 = (const float*)d_in[18];
  const float* w7 = (const float*)d_in[19];
  const float* b7 = (const float*)d_in[20];
  const float* sW1 = (const float*)d_in[21];
  const float* sb1 = (const float*)d_in[22];
  const float* sW2 = (const float*)d_in[23];
  const float* sb2 = (const float*)d_in[24];
  const float* nW1 = (const float*)d_in[25];
  const float* nb1 = (const float*)d_in[26];
  const float* nW2 = (const float*)d_in[27];
  const float* nb2 = (const float*)d_in[28];

  __hip_bfloat16* Xbr = (__hip_bfloat16*)d_ws;          // 3,244,032
  __hip_bfloat16* Wbr = Xbr + (size_t)3244032;          //   946,176
  __hip_bfloat16* W1br = Wbr + (size_t)946176;          //   917,504
  __hip_bfloat16* candb = W1br + (size_t)917504;        //   163,840
  __hip_bfloat16* eb = candb + (size_t)163840;          //     8,192
  __hip_bfloat16* typeb = eb + (size_t)8192;            //   640,000
  __hip_bfloat16* relb = typeb + (size_t)640000;        //    64,000
  __hip_bfloat16* relwb = relb + (size_t)64000;         //    16,384
  float* ctxpool = (float*)(relwb + (size_t)16384);     //    49,152 f32
  float* part = ctxpool + (size_t)B * CTX_DIM;          //    20,480 f32
  float* part_n = part + (size_t)16 * B * N_CANDS;      //     1,024 f32
  float* out = (float*)d_out;

  hipLaunchKernelGGL(k_prep, dim3(2167), dim3(256), 0, stream, type_emb,
                     rel_emb, rel_weight, typeb, relb, relwb, tokens, pos,
                     word_embs, pos_emb, Xbr, w3, w5, w7, Wbr, sW1, nW1, W1br,
                     ctxpool);
  hipLaunchKernelGGL(k_cand, dim3(B * N_CANDS), dim3(256), 0, stream, nb_types,
                     nb_n_types, nb_rs, typeb, relb, relwb, candb);
  hipLaunchKernelGGL(k_conv_mfma, dim3(B, 2, 6), dim3(256), 0, stream, Xbr,
                     Wbr, pos, masks, b3, b5, b7, ctxpool);
  hipLaunchKernelGGL(k_mlp_gemm, dim3(40, 4), dim3(256), 0, stream, ctxpool,
                     candb, W1br, 0, sb1, sW2, part, 20, B * N_CANDS);
  hipLaunchKernelGGL(k_softmax_e, dim3(B), dim3(128), 0, stream, part, candb,
                     real_n_poss, sb2, out, eb);
  hipLaunchKernelGGL(k_mlp_gemm, dim3(2, 4), dim3(256), 0, stream, ctxpool, eb,
                     W1br, 1, nb1, nW2, part_n, 1, B);
  hipLaunchKernelGGL(k_noise_fin, dim3(1), dim3(64), 0, stream, part_n, nb2,
                     out);
}

// Round 6
// 121.220 us; speedup vs baseline: 1.2750x; 1.0604x over previous
//
#include <hip/hip_runtime.h>
#include <hip/hip_bf16.h>

#define B 64
#define L 100
#define WDIM 300
#define PDIM 50
#define DIM 350
#define NK0 11              // 352/32 k-chunks
#define BRICK_ROWS 144      // rows per (b,k0) brick; row r -> l' = r-3
#define NSHIFT 7
#define NKK 77              // 11 k0 * 7 shifts
#define N_CANDS 20
#define N_POSS 10
#define NB_PER_CAND 64
#define TDIM 128
#define EDIM 128
#define CTX_DIM 768
#define EN_HID1 896
#define EN_DIM 512
#define NEG_INF_F 1.0e10f

typedef __attribute__((ext_vector_type(8))) short bf16x8;
typedef __attribute__((ext_vector_type(4))) float f32x4;
typedef __attribute__((ext_vector_type(16))) float f32x16;

__device__ __forceinline__ void gload_lds16(const __hip_bfloat16* g,
                                            __hip_bfloat16* l) {
  __builtin_amdgcn_global_load_lds(
      (const __attribute__((address_space(1))) unsigned int*)(g),
      (__attribute__((address_space(3))) unsigned int*)(l), 16, 0, 0);
}

__device__ __forceinline__ bf16x8 cvt8(float4 a, float4 b) {
  union { bf16x8 v; __hip_bfloat16 h[8]; } u;
  u.h[0] = __float2bfloat16(a.x); u.h[1] = __float2bfloat16(a.y);
  u.h[2] = __float2bfloat16(a.z); u.h[3] = __float2bfloat16(a.w);
  u.h[4] = __float2bfloat16(b.x); u.h[5] = __float2bfloat16(b.y);
  u.h[6] = __float2bfloat16(b.z); u.h[7] = __float2bfloat16(b.w);
  return u.v;
}

// ---------------------------------------------------------------------------
// K1 k_front (fused): [0,1280) cand; [1280,2432) Xbr; [2432,2663) Wbr;
// [2663,2695) W1br; [2695,2743) ctxpool init.
__global__ __launch_bounds__(256) void k_front(
    const int* __restrict__ nb_types, const int* __restrict__ nb_n_types,
    const int* __restrict__ nb_rs, const float* __restrict__ type_emb,
    const float* __restrict__ rel_emb, const float* __restrict__ rel_weight,
    __hip_bfloat16* __restrict__ candb, const int* __restrict__ tokens,
    const int* __restrict__ pos, const float* __restrict__ word_embs,
    const float* __restrict__ pos_emb, __hip_bfloat16* __restrict__ Xbr,
    const float* __restrict__ w3, const float* __restrict__ w5,
    const float* __restrict__ w7, __hip_bfloat16* __restrict__ Wbr,
    const float* __restrict__ sW1, const float* __restrict__ nW1,
    __hip_bfloat16* __restrict__ W1br, float* __restrict__ ctxpool) {
  int blk = blockIdx.x, tid = threadIdx.x;
  __shared__ int sty[NB_PER_CAND * 4];
  __shared__ int srs[NB_PER_CAND];
  __shared__ float sinv[NB_PER_CAND];
  __shared__ float pS[2][128], pR[2][128], sS[128];

  if (blk < 1280) {  // ---- cand (f32 tables)
    int c = blk;
    int g = tid >> 7, d = tid & 127;
    sty[tid] = nb_types[c * NB_PER_CAND * 4 + tid];
    if (tid < NB_PER_CAND) {
      srs[tid] = nb_rs[c * NB_PER_CAND + tid];
      sinv[tid] = 1.f / (float)nb_n_types[c * NB_PER_CAND + tid];
    }
    __syncthreads();
    float accS = 0.f, accR = 0.f;
#pragma unroll 4
    for (int j2 = 0; j2 < 32; ++j2) {
      int j = g * 32 + j2;
      accR += rel_emb[srs[j] * EDIM + d];
      float s4 = 0.f;
#pragma unroll
      for (int k = 0; k < 4; ++k) s4 += type_emb[sty[j * 4 + k] * TDIM + d];
      accS = fmaf(s4, sinv[j], accS);
    }
    pS[g][d] = accS;
    pR[g][d] = accR;
    __syncthreads();
    if (tid < 128) sS[d] = pS[0][d] + pS[1][d];
    __syncthreads();
    float dotp = (g == 0) ? (pR[0][d] + pR[1][d]) : 0.f;
#pragma unroll 4
    for (int k2 = 0; k2 < 64; ++k2) {
      int k = g * 64 + k2;
      dotp = fmaf(sS[k], rel_weight[k * EDIM + d], dotp);
    }
    pS[g][d] = dotp;
    __syncthreads();
    if (tid < 128)
      candb[(size_t)c * EDIM + d] =
          __float2bfloat16(fmaxf(pS[0][d] + pS[1][d], 0.f));
  } else if (blk < 2432) {  // ---- Xbr bricks
    int idx = blk - 1280;
    int b = idx / 18, r0 = (idx % 18) * 8;
    __hip_bfloat16* base = Xbr + (size_t)b * (NK0 * BRICK_ROWS * 32);
    for (int r = r0; r < r0 + 8; ++r) {
      int lp = r - 3;
      if (lp >= 0 && lp < L) {
        int tok = tokens[b * L + lp];
        int pp = pos[b * L + lp] + 100;
        const float* wrow = word_embs + (size_t)tok * WDIM;
        const float* prow = pos_emb + (size_t)pp * PDIM;
        for (int d = tid; d < 352; d += 256) {
          float v = (d < WDIM) ? wrow[d] : (d < DIM) ? prow[d - WDIM] : 0.f;
          base[((size_t)(d >> 5) * BRICK_ROWS + r) * 32 + (d & 31)] =
              __float2bfloat16(v);
        }
      } else {
        for (int d = tid; d < 352; d += 256)
          base[((size_t)(d >> 5) * BRICK_ROWS + r) * 32 + (d & 31)] =
              __float2bfloat16(0.f);
      }
    }
  } else if (blk < 2663) {  // ---- Wbr bricks
    int idx = blk - 2432;
    int ncg = idx / NKK, kkb = idx % NKK;
    if (tid < 128) {
      int k0 = kkb / NSHIFT, s = kkb - NSHIFT * k0;
      int col = tid;
      const float* w = (ncg == 0) ? w3 : (ncg == 1) ? w5 : w7;
      int fs = (ncg == 0) ? 3 : (ncg == 1) ? 5 : 7;
      int dl = (ncg == 0) ? s - 2 : (ncg == 1) ? s - 1 : s;
      bool valid = (dl >= 0 && dl < fs);
      __hip_bfloat16* dst = Wbr + (((size_t)ncg * NKK + kkb) * 128 + col) * 32;
      for (int k = 0; k < 32; ++k) {
        int d = k0 * 32 + k;
        float v =
            (valid && d < DIM) ? w[((size_t)col * fs + dl) * DIM + d] : 0.f;
        dst[k] = __float2bfloat16(v);
      }
    }
  } else if (blk < 2695) {  // ---- W1br bricks
    int idx = blk - 2663;
    int which = idx >> 4, sub = idx & 15;
    const float* src = which ? nW1 : sW1;
    __hip_bfloat16* dst = W1br + (size_t)which * (16 * 56 * 512);
    for (int i = tid; i < 32 * EN_HID1; i += 256) {
      int col = i / EN_HID1, k = i - col * EN_HID1;
      float v = src[(size_t)k * EN_DIM + sub * 32 + col];
      dst[((size_t)(sub * 56 + (k >> 4)) * 32 + col) * 16 + (k & 15)] =
          __float2bfloat16(v);
    }
  } else {  // ---- ctxpool init
    int idx = blk - 2695;
    int i0 = idx * 1024 + tid * 4;
#pragma unroll
    for (int q = 0; q < 4; ++q) ctxpool[i0 + q] = -NEG_INF_F;
  }
}

// ---------------------------------------------------------------------------
// K2 conv: 11 barrier-steps. A (80 rows x 32k) LDS double-buffered via
// global_load_lds (exactly 5 x 1KB segments -> NO overflow); B direct from
// L2-resident Wbr. Per k0: 7 shifts x 4 MFMA(16x16x32). Pool via atomicMax.
__global__ __launch_bounds__(256) void k_conv(
    const __hip_bfloat16* __restrict__ Xbr,
    const __hip_bfloat16* __restrict__ Wbr, const int* __restrict__ pos,
    const float* __restrict__ masks, const float* __restrict__ b3,
    const float* __restrict__ b5, const float* __restrict__ b7,
    float* __restrict__ ctxpool) {
  int b = blockIdx.x;
  int mt = blockIdx.y;  // 0..1
  int nt = blockIdx.z;  // 0..5
  int ncg = nt >> 1, nh = nt & 1;
  int tid = threadIdx.x;
  int wv = tid >> 6, ln = tid & 63;
  int wm = wv >> 1, wn = wv & 1;
  int l15 = ln & 15, kg = ln >> 4;

  __shared__ __align__(16) __hip_bfloat16 Asb[2][80 * 32];
  __shared__ float sml[64], smr[64];

  if (tid < 64) {
    int l = mt * 64 + tid;
    float mlv = 0.f, mrv = 0.f;
    if (l < L) {
      int p = pos[b * L + l];
      mlv = (p <= 0) ? 1.f : 0.f;
      mrv = (p >= 0) ? masks[b * L + l] : 0.f;
    }
    sml[tid] = mlv;
    smr[tid] = mrv;
  }

  const __hip_bfloat16* XB =
      Xbr + (size_t)b * (NK0 * BRICK_ROWS * 32) + (size_t)mt * 64 * 32;
  const __hip_bfloat16* WBl =
      Wbr + ((size_t)ncg * NKK * 128 + nh * 64 + wn * 32 + l15) * 32 + kg * 8;

  for (int seg = wv; seg < 5; seg += 4)
    gload_lds16(XB + (seg * 64 + ln) * 8, &Asb[0][(seg * 64 + ln) * 8]);
  __syncthreads();

  f32x4 acc[2][2];
#pragma unroll
  for (int i = 0; i < 2; ++i)
#pragma unroll
    for (int j = 0; j < 2; ++j) acc[i][j] = (f32x4){0.f, 0.f, 0.f, 0.f};

  int buf = 0;
  for (int k0 = 0; k0 < NK0; ++k0) {
    if (k0 < NK0 - 1) {
      const __hip_bfloat16* asrc = XB + (size_t)(k0 + 1) * (BRICK_ROWS * 32);
      for (int seg = wv; seg < 5; seg += 4)
        gload_lds16(asrc + (seg * 64 + ln) * 8,
                    &Asb[buf ^ 1][(seg * 64 + ln) * 8]);
    }
#pragma unroll
    for (int s = 0; s < NSHIFT; ++s) {
      const __hip_bfloat16* bp = WBl + (size_t)(k0 * NSHIFT + s) * 4096;
      bf16x8 bf0 = *(const bf16x8*)(bp);
      bf16x8 bf1 = *(const bf16x8*)(bp + 512);
      int rbase = wm * 32 + l15 + s;
      bf16x8 af0 = *(const bf16x8*)&Asb[buf][rbase * 32 + kg * 8];
      bf16x8 af1 = *(const bf16x8*)&Asb[buf][(rbase + 16) * 32 + kg * 8];
      acc[0][0] = __builtin_amdgcn_mfma_f32_16x16x32_bf16(af0, bf0, acc[0][0], 0, 0, 0);
      acc[0][1] = __builtin_amdgcn_mfma_f32_16x16x32_bf16(af0, bf1, acc[0][1], 0, 0, 0);
      acc[1][0] = __builtin_amdgcn_mfma_f32_16x16x32_bf16(af1, bf0, acc[1][0], 0, 0, 0);
      acc[1][1] = __builtin_amdgcn_mfma_f32_16x16x32_bf16(af1, bf1, acc[1][1], 0, 0, 0);
    }
    __syncthreads();
    buf ^= 1;
  }

  const float* barr = (ncg == 0) ? b3 : (ncg == 1) ? b5 : b7;
#pragma unroll
  for (int j = 0; j < 2; ++j) {
    int fcol = nh * 64 + wn * 32 + 16 * j + l15;
    float bias = barr[fcol];
    float mpl = -NEG_INF_F, mpr = -NEG_INF_F;
#pragma unroll
    for (int i = 0; i < 2; ++i) {
#pragma unroll
      for (int r = 0; r < 4; ++r) {
        int rl = wm * 32 + 16 * i + 4 * kg + r;
        float cva = fmaxf(acc[i][j][r] + bias, 0.f);
        float ml = sml[rl], mr = smr[rl];
        mpl = fmaxf(mpl, cva * ml - (1.f - ml) * NEG_INF_F);
        mpr = fmaxf(mpr, cva * mr - (1.f - mr) * NEG_INF_F);
      }
    }
    mpl = fmaxf(mpl, __shfl_xor(mpl, 16));
    mpl = fmaxf(mpl, __shfl_xor(mpl, 32));
    mpr = fmaxf(mpr, __shfl_xor(mpr, 16));
    mpr = fmaxf(mpr, __shfl_xor(mpr, 32));
    if (ln < 16) {
      atomicMax((int*)&ctxpool[(size_t)b * CTX_DIM + ncg * 128 + fcol],
                __float_as_int(mpl));
      atomicMax((int*)&ctxpool[(size_t)b * CTX_DIM + 384 + ncg * 128 + fcol],
                __float_as_int(mpr));
    }
  }
}

// ---------------------------------------------------------------------------
// K3: scorer GEMM (mt<40, K=896, epilogue relu*W2 -> partials) + noise
// ctx-part (mt 40..41, K=768, raw pre-activation -> hctxn[64][512]).
__global__ __launch_bounds__(256) void k_mlp(
    const float* __restrict__ ctxp, const __hip_bfloat16* __restrict__ candb,
    const __hip_bfloat16* __restrict__ W1br, const float* __restrict__ sb1,
    const float* __restrict__ sW2, float* __restrict__ part,
    float* __restrict__ hctxn) {
  int mt = blockIdx.x;
  bool noise = (mt >= 40);
  int w = threadIdx.x >> 6;
  int sub = blockIdx.y * 4 + w;
  int lane = threadIdx.x & 63;
  int lrow = lane & 31, kg2 = lane >> 5;
  __shared__ __align__(16) __hip_bfloat16 As[32][904];

  {
    int row = threadIdx.x >> 3, seg = threadIdx.x & 7;
    if (!noise) {
      int m = mt * 32 + row;
      int bb = m / 20;
      const float* cp = ctxp + (size_t)bb * CTX_DIM;
#pragma unroll
      for (int q = 0; q < 14; ++q) {
        int k = seg * 112 + q * 8;
        bf16x8 v;
        if (k < CTX_DIM)
          v = cvt8(*(const float4*)(cp + k), *(const float4*)(cp + k + 4));
        else
          v = *(const bf16x8*)&candb[(size_t)m * EDIM + (k - CTX_DIM)];
        *(bf16x8*)&As[row][k] = v;
      }
    } else {
      int bb = (mt - 40) * 32 + row;
      const float* cp = ctxp + (size_t)bb * CTX_DIM;
#pragma unroll
      for (int q = 0; q < 14; ++q) {
        int k = seg * 112 + q * 8;
        if (k < CTX_DIM)
          *(bf16x8*)&As[row][k] =
              cvt8(*(const float4*)(cp + k), *(const float4*)(cp + k + 4));
      }
    }
  }
  __syncthreads();

  f32x16 acc = {};
  if (!noise) {
    const __hip_bfloat16* W1b = W1br;
#pragma unroll 4
    for (int k0 = 0; k0 < 56; ++k0) {
      bf16x8 av = *(const bf16x8*)&As[lrow][k0 * 16 + kg2 * 8];
      bf16x8 bv = *(const bf16x8*)&W1b[((size_t)sub * 56 + k0) * 512 +
                                       lrow * 16 + kg2 * 8];
      acc = __builtin_amdgcn_mfma_f32_32x32x16_bf16(av, bv, acc, 0, 0, 0);
    }
    int n = sub * 32 + lrow;
    float b1n = sb1[n], w2n = sW2[n];
#pragma unroll
    for (int r = 0; r < 16; ++r) {
      float v = fmaxf(acc[r] + b1n, 0.f) * w2n;
#pragma unroll
      for (int off = 16; off; off >>= 1) v += __shfl_xor(v, off);
      if (lrow == 0) {
        int mm = mt * 32 + (r & 3) + 8 * (r >> 2) + 4 * kg2;
        part[(size_t)sub * (B * N_CANDS) + mm] = v;
      }
    }
  } else {
    const __hip_bfloat16* W1b = W1br + (size_t)(16 * 56 * 512);
#pragma unroll 4
    for (int k0 = 0; k0 < 48; ++k0) {
      bf16x8 av = *(const bf16x8*)&As[lrow][k0 * 16 + kg2 * 8];
      bf16x8 bv = *(const bf16x8*)&W1b[((size_t)sub * 56 + k0) * 512 +
                                       lrow * 16 + kg2 * 8];
      acc = __builtin_amdgcn_mfma_f32_32x32x16_bf16(av, bv, acc, 0, 0, 0);
    }
#pragma unroll
    for (int r = 0; r < 16; ++r) {
      int mrow = (r & 3) + 8 * (r >> 2) + 4 * kg2;
      hctxn[(size_t)((mt - 40) * 32 + mrow) * EN_DIM + sub * 32 + lrow] =
          acc[r];
    }
  }
}

// ---------------------------------------------------------------------------
// K4 tail (2 blocks x 512): scores finish+write, softmax(10), e, noise
// finish (K=128 MFMA vs nW1 e-bricks + hctxn partial), final sum, write.
__global__ __launch_bounds__(512) void k_tail(
    const float* __restrict__ part, const __hip_bfloat16* __restrict__ candb,
    const float* __restrict__ hctxn, const int* __restrict__ real_n_poss,
    const float* __restrict__ sb2, const __hip_bfloat16* __restrict__ W1br,
    const float* __restrict__ nb1, const float* __restrict__ nW2,
    const float* __restrict__ nb2, float* __restrict__ out) {
  int mt = blockIdx.x;  // 0..1 -> 32 b each
  int tid = threadIdx.x;
  __shared__ float ssc[32][20];
  __shared__ float sp[32][10];
  __shared__ __align__(16) __hip_bfloat16 e_lds[32][136];
  __shared__ float part_d[16][32];

  float sb2v = sb2[0];
  for (int i = tid; i < 640; i += 512) {
    int lb = i / 20, c = i - lb * 20;
    int bg = mt * 32 + lb, m = bg * 20 + c;
    float s = sb2v;
#pragma unroll
    for (int p = 0; p < 16; ++p) s += part[(size_t)p * (B * N_CANDS) + m];
    if (c < N_POSS && (c + 1) > real_n_poss[bg]) s = -NEG_INF_F;
    ssc[lb][c] = s;
    out[m] = s;
  }
  __syncthreads();
  if (tid < 32) {
    float mx = -INFINITY;
#pragma unroll
    for (int c = 0; c < N_POSS; ++c) mx = fmaxf(mx, ssc[tid][c]);
    float ssum = 0.f;
    float pe[N_POSS];
#pragma unroll
    for (int c = 0; c < N_POSS; ++c) {
      pe[c] = expf(ssc[tid][c] - mx);
      ssum += pe[c];
    }
    float inv = 1.f / ssum;
#pragma unroll
    for (int c = 0; c < N_POSS; ++c) sp[tid][c] = pe[c] * inv;
  }
  __syncthreads();
  for (int i = tid; i < 32 * 128; i += 512) {
    int lb = i >> 7, d = i & 127;
    int bg = mt * 32 + lb;
    float ev = 0.f;
#pragma unroll
    for (int c = 0; c < N_POSS; ++c)
      ev = fmaf(sp[lb][c],
                __bfloat162float(candb[(size_t)(bg * N_CANDS + c) * EDIM + d]),
                ev);
    e_lds[lb][d] = __float2bfloat16(ev);
  }
  __syncthreads();

  int w = tid >> 6, lane = tid & 63;
  int lrow = lane & 31, kg2 = lane >> 5;
  const __hip_bfloat16* W1n = W1br + (size_t)(16 * 56 * 512);
  for (int sp2 = 0; sp2 < 2; ++sp2) {
    int sub = w * 2 + sp2;
    f32x16 acc = {};
#pragma unroll
    for (int k0 = 0; k0 < 8; ++k0) {
      bf16x8 av = *(const bf16x8*)&e_lds[lrow][k0 * 16 + kg2 * 8];
      bf16x8 bv = *(const bf16x8*)&W1n[((size_t)sub * 56 + 48 + k0) * 512 +
                                       lrow * 16 + kg2 * 8];
      acc = __builtin_amdgcn_mfma_f32_32x32x16_bf16(av, bv, acc, 0, 0, 0);
    }
    int n = sub * 32 + lrow;
    float b1n = nb1[n], w2n = nW2[n];
#pragma unroll
    for (int r = 0; r < 16; ++r) {
      int mrow = (r & 3) + 8 * (r >> 2) + 4 * kg2;
      float v =
          fmaxf(acc[r] + hctxn[(size_t)(mt * 32 + mrow) * EN_DIM + n] + b1n,
                0.f) *
          w2n;
#pragma unroll
      for (int off = 16; off; off >>= 1) v += __shfl_xor(v, off);
      if (lrow == 0) part_d[sub][mrow] = v;
    }
  }
  __syncthreads();
  if (tid < 32) {
    float s = nb2[0];
#pragma unroll
    for (int q = 0; q < 16; ++q) s += part_d[q][tid];
    out[B * N_CANDS + mt * 32 + tid] = s;
  }
}

// ---------------------------------------------------------------------------
extern "C" void kernel_launch(void* const* d_in, const int* in_sizes, int n_in,
                              void* d_out, int out_size, void* d_ws,
                              size_t ws_size, hipStream_t stream) {
  const int* tokens = (const int*)d_in[0];
  const int* pos = (const int*)d_in[1];
  const float* masks = (const float*)d_in[2];
  const int* nb_types = (const int*)d_in[3];
  const int* nb_n_types = (const int*)d_in[5];
  const int* nb_rs = (const int*)d_in[6];
  const int* real_n_poss = (const int*)d_in[8];
  const float* word_embs = (const float*)d_in[10];
  const float* pos_emb = (const float*)d_in[11];
  const float* type_emb = (const float*)d_in[12];
  const float* rel_emb = (const float*)d_in[13];
  const float* rel_weight = (const float*)d_in[14];
  const float* w3 = (const float*)d_in[15];
  const float* b3 = (const float*)d_in[16];
  const float* w5 = (const float*)d_in[17];
  const float* b5 = (const float*)d_in[18];
  const float* w7 = (const float*)d_in[19];
  const float* b7 = (const float*)d_in[20];
  const float* sW1 = (const float*)d_in[21];
  const float* sb1 = (const float*)d_in[22];
  const float* sW2 = (const float*)d_in[23];
  const float* sb2 = (const float*)d_in[24];
  const float* nW1 = (const float*)d_in[25];
  const float* nb1 = (const float*)d_in[26];
  const float* nW2 = (const float*)d_in[27];
  const float* nb2 = (const float*)d_in[28];

  __hip_bfloat16* Xbr = (__hip_bfloat16*)d_ws;          // 3,244,032 bf16
  __hip_bfloat16* Wbr = Xbr + (size_t)3244032;          //   946,176
  __hip_bfloat16* W1br = Wbr + (size_t)946176;          //   917,504
  __hip_bfloat16* candb = W1br + (size_t)917504;        //   163,840
  float* ctxpool = (float*)(candb + (size_t)163840);    //    49,152 f32
  float* part = ctxpool + (size_t)B * CTX_DIM;          //    20,480 f32
  float* hctxn = part + (size_t)16 * B * N_CANDS;       //    32,768 f32
  float* out = (float*)d_out;

  hipLaunchKernelGGL(k_front, dim3(2743), dim3(256), 0, stream, nb_types,
                     nb_n_types, nb_rs, type_emb, rel_emb, rel_weight, candb,
                     tokens, pos, word_embs, pos_emb, Xbr, w3, w5, w7, Wbr,
                     sW1, nW1, W1br, ctxpool);
  hipLaunchKernelGGL(k_conv, dim3(B, 2, 6), dim3(256), 0, stream, Xbr, Wbr,
                     pos, masks, b3, b5, b7, ctxpool);
  hipLaunchKernelGGL(k_mlp, dim3(42, 4), dim3(256), 0, stream, ctxpool, candb,
                     W1br, sb1, sW2, part, hctxn);
  hipLaunchKernelGGL(k_tail, dim3(2), dim3(512), 0, stream, part, candb,
                     hctxn, real_n_poss, sb2, W1br, nb1, nW2, nb2, out);
}

// Round 7
// 109.509 us; speedup vs baseline: 1.4114x; 1.1069x over previous
//
#include <hip/hip_runtime.h>
#include <hip/hip_bf16.h>

#define B 64
#define L 100
#define WDIM 300
#define PDIM 50
#define DIM 350
#define NK0 11              // 352/32 k-chunks
#define BRICK_ROWS 144      // rows per (b,k0) brick; row r -> l' = r-3
#define NSHIFT 7
#define NKK 77              // 11 k0 * 7 shifts
#define N_CANDS 20
#define N_POSS 10
#define NB_PER_CAND 64
#define TDIM 128
#define EDIM 128
#define CTX_DIM 768
#define EN_HID1 896
#define EN_DIM 512
#define NEG_INF_F 1.0e10f

typedef __attribute__((ext_vector_type(8))) short bf16x8;
typedef __attribute__((ext_vector_type(4))) float f32x4;
typedef __attribute__((ext_vector_type(16))) float f32x16;

__device__ __forceinline__ void gload_lds16(const __hip_bfloat16* g,
                                            __hip_bfloat16* l) {
  __builtin_amdgcn_global_load_lds(
      (const __attribute__((address_space(1))) unsigned int*)(g),
      (__attribute__((address_space(3))) unsigned int*)(l), 16, 0, 0);
}

__device__ __forceinline__ bf16x8 cvt8(float4 a, float4 b) {
  union { bf16x8 v; __hip_bfloat16 h[8]; } u;
  u.h[0] = __float2bfloat16(a.x); u.h[1] = __float2bfloat16(a.y);
  u.h[2] = __float2bfloat16(a.z); u.h[3] = __float2bfloat16(a.w);
  u.h[4] = __float2bfloat16(b.x); u.h[5] = __float2bfloat16(b.y);
  u.h[6] = __float2bfloat16(b.z); u.h[7] = __float2bfloat16(b.w);
  return u.v;
}

// ---------------------------------------------------------------------------
// K1 k_front (fused): [0,1280) cand; [1280,2432) Xbr (pre-swizzled for the
// conv's LDS read pattern: 16B slot ^= (row>>1)&3); [2432,2663) Wbr;
// [2663,2695) W1br; [2695,2743) ctxpool init.
__global__ __launch_bounds__(256) void k_front(
    const int* __restrict__ nb_types, const int* __restrict__ nb_n_types,
    const int* __restrict__ nb_rs, const float* __restrict__ type_emb,
    const float* __restrict__ rel_emb, const float* __restrict__ rel_weight,
    __hip_bfloat16* __restrict__ candb, const int* __restrict__ tokens,
    const int* __restrict__ pos, const float* __restrict__ word_embs,
    const float* __restrict__ pos_emb, __hip_bfloat16* __restrict__ Xbr,
    const float* __restrict__ w3, const float* __restrict__ w5,
    const float* __restrict__ w7, __hip_bfloat16* __restrict__ Wbr,
    const float* __restrict__ sW1, const float* __restrict__ nW1,
    __hip_bfloat16* __restrict__ W1br, float* __restrict__ ctxpool) {
  int blk = blockIdx.x, tid = threadIdx.x;
  __shared__ int sty[NB_PER_CAND * 4];
  __shared__ int srs[NB_PER_CAND];
  __shared__ float sinv[NB_PER_CAND];
  __shared__ float pS[2][128], pR[2][128], sS[128];

  if (blk < 1280) {  // ---- cand (f32 tables)
    int c = blk;
    int g = tid >> 7, d = tid & 127;
    sty[tid] = nb_types[c * NB_PER_CAND * 4 + tid];
    if (tid < NB_PER_CAND) {
      srs[tid] = nb_rs[c * NB_PER_CAND + tid];
      sinv[tid] = 1.f / (float)nb_n_types[c * NB_PER_CAND + tid];
    }
    __syncthreads();
    float accS = 0.f, accR = 0.f;
#pragma unroll 4
    for (int j2 = 0; j2 < 32; ++j2) {
      int j = g * 32 + j2;
      accR += rel_emb[srs[j] * EDIM + d];
      float s4 = 0.f;
#pragma unroll
      for (int k = 0; k < 4; ++k) s4 += type_emb[sty[j * 4 + k] * TDIM + d];
      accS = fmaf(s4, sinv[j], accS);
    }
    pS[g][d] = accS;
    pR[g][d] = accR;
    __syncthreads();
    if (tid < 128) sS[d] = pS[0][d] + pS[1][d];
    __syncthreads();
    float dotp = (g == 0) ? (pR[0][d] + pR[1][d]) : 0.f;
#pragma unroll 4
    for (int k2 = 0; k2 < 64; ++k2) {
      int k = g * 64 + k2;
      dotp = fmaf(sS[k], rel_weight[k * EDIM + d], dotp);
    }
    pS[g][d] = dotp;
    __syncthreads();
    if (tid < 128)
      candb[(size_t)c * EDIM + d] =
          __float2bfloat16(fmaxf(pS[0][d] + pS[1][d], 0.f));
  } else if (blk < 2432) {  // ---- Xbr bricks (swizzled)
    int idx = blk - 1280;
    int b = idx / 18, r0 = (idx % 18) * 8;
    __hip_bfloat16* base = Xbr + (size_t)b * (NK0 * BRICK_ROWS * 32);
    for (int r = r0; r < r0 + 8; ++r) {
      int lp = r - 3;
      int xr = (r >> 1) & 3;
      if (lp >= 0 && lp < L) {
        int tok = tokens[b * L + lp];
        int pp = pos[b * L + lp] + 100;
        const float* wrow = word_embs + (size_t)tok * WDIM;
        const float* prow = pos_emb + (size_t)pp * PDIM;
        for (int d = tid; d < 352; d += 256) {
          float v = (d < WDIM) ? wrow[d] : (d < DIM) ? prow[d - WDIM] : 0.f;
          int slot = (d >> 3) & 3;
          base[((size_t)(d >> 5) * BRICK_ROWS + r) * 32 +
               ((slot ^ xr) << 3) + (d & 7)] = __float2bfloat16(v);
        }
      } else {
        for (int d = tid; d < 352; d += 256) {
          int slot = (d >> 3) & 3;
          base[((size_t)(d >> 5) * BRICK_ROWS + r) * 32 +
               ((slot ^ xr) << 3) + (d & 7)] = __float2bfloat16(0.f);
        }
      }
    }
  } else if (blk < 2663) {  // ---- Wbr bricks
    int idx = blk - 2432;
    int ncg = idx / NKK, kkb = idx % NKK;
    if (tid < 128) {
      int k0 = kkb / NSHIFT, s = kkb - NSHIFT * k0;
      int col = tid;
      const float* w = (ncg == 0) ? w3 : (ncg == 1) ? w5 : w7;
      int fs = (ncg == 0) ? 3 : (ncg == 1) ? 5 : 7;
      int dl = (ncg == 0) ? s - 2 : (ncg == 1) ? s - 1 : s;
      bool valid = (dl >= 0 && dl < fs);
      __hip_bfloat16* dst = Wbr + (((size_t)ncg * NKK + kkb) * 128 + col) * 32;
      for (int k = 0; k < 32; ++k) {
        int d = k0 * 32 + k;
        float v =
            (valid && d < DIM) ? w[((size_t)col * fs + dl) * DIM + d] : 0.f;
        dst[k] = __float2bfloat16(v);
      }
    }
  } else if (blk < 2695) {  // ---- W1br bricks
    int idx = blk - 2663;
    int which = idx >> 4, sub = idx & 15;
    const float* src = which ? nW1 : sW1;
    __hip_bfloat16* dst = W1br + (size_t)which * (16 * 56 * 512);
    for (int i = tid; i < 32 * EN_HID1; i += 256) {
      int col = i / EN_HID1, k = i - col * EN_HID1;
      float v = src[(size_t)k * EN_DIM + sub * 32 + col];
      dst[((size_t)(sub * 56 + (k >> 4)) * 32 + col) * 16 + (k & 15)] =
          __float2bfloat16(v);
    }
  } else {  // ---- ctxpool init
    int idx = blk - 2695;
    int i0 = idx * 1024 + tid * 4;
#pragma unroll
    for (int q = 0; q < 4; ++q) ctxpool[i0 + q] = -NEG_INF_F;
  }
}

// ---------------------------------------------------------------------------
// K2 conv: 11 barrier-steps. A (80 rows x 32k) LDS double-buffered via
// global_load_lds from the pre-swizzled Xbr (linear dest + swizzled read =
// 2-way banks); B direct from L2-resident Wbr. 7 shifts x 4 MFMA per k0.
__global__ __launch_bounds__(256) void k_conv(
    const __hip_bfloat16* __restrict__ Xbr,
    const __hip_bfloat16* __restrict__ Wbr, const int* __restrict__ pos,
    const float* __restrict__ masks, const float* __restrict__ b3,
    const float* __restrict__ b5, const float* __restrict__ b7,
    float* __restrict__ ctxpool) {
  int b = blockIdx.x;
  int mt = blockIdx.y;  // 0..1
  int nt = blockIdx.z;  // 0..5
  int ncg = nt >> 1, nh = nt & 1;
  int tid = threadIdx.x;
  int wv = tid >> 6, ln = tid & 63;
  int wm = wv >> 1, wn = wv & 1;
  int l15 = ln & 15, kg = ln >> 4;

  __shared__ __align__(16) __hip_bfloat16 Asb[2][80 * 32];
  __shared__ float sml[64], smr[64];

  if (tid < 64) {
    int l = mt * 64 + tid;
    float mlv = 0.f, mrv = 0.f;
    if (l < L) {
      int p = pos[b * L + l];
      mlv = (p <= 0) ? 1.f : 0.f;
      mrv = (p >= 0) ? masks[b * L + l] : 0.f;
    }
    sml[tid] = mlv;
    smr[tid] = mrv;
  }

  const __hip_bfloat16* XB =
      Xbr + (size_t)b * (NK0 * BRICK_ROWS * 32) + (size_t)mt * 64 * 32;
  const __hip_bfloat16* WBl =
      Wbr + ((size_t)ncg * NKK * 128 + nh * 64 + wn * 32 + l15) * 32 + kg * 8;

  for (int seg = wv; seg < 5; seg += 4)
    gload_lds16(XB + (seg * 64 + ln) * 8, &Asb[0][(seg * 64 + ln) * 8]);
  __syncthreads();

  f32x4 acc[2][2];
#pragma unroll
  for (int i = 0; i < 2; ++i)
#pragma unroll
    for (int j = 0; j < 2; ++j) acc[i][j] = (f32x4){0.f, 0.f, 0.f, 0.f};

  int buf = 0;
  for (int k0 = 0; k0 < NK0; ++k0) {
    if (k0 < NK0 - 1) {
      const __hip_bfloat16* asrc = XB + (size_t)(k0 + 1) * (BRICK_ROWS * 32);
      for (int seg = wv; seg < 5; seg += 4)
        gload_lds16(asrc + (seg * 64 + ln) * 8,
                    &Asb[buf ^ 1][(seg * 64 + ln) * 8]);
    }
#pragma unroll
    for (int s = 0; s < NSHIFT; ++s) {
      const __hip_bfloat16* bp = WBl + (size_t)(k0 * NSHIFT + s) * 4096;
      bf16x8 bf0 = *(const bf16x8*)(bp);
      bf16x8 bf1 = *(const bf16x8*)(bp + 512);
      int rbase = wm * 32 + l15 + s;
      int xr = (kg ^ ((rbase >> 1) & 3)) << 3;
      bf16x8 af0 = *(const bf16x8*)&Asb[buf][rbase * 32 + xr];
      bf16x8 af1 = *(const bf16x8*)&Asb[buf][(rbase + 16) * 32 + xr];
      acc[0][0] = __builtin_amdgcn_mfma_f32_16x16x32_bf16(af0, bf0, acc[0][0], 0, 0, 0);
      acc[0][1] = __builtin_amdgcn_mfma_f32_16x16x32_bf16(af0, bf1, acc[0][1], 0, 0, 0);
      acc[1][0] = __builtin_amdgcn_mfma_f32_16x16x32_bf16(af1, bf0, acc[1][0], 0, 0, 0);
      acc[1][1] = __builtin_amdgcn_mfma_f32_16x16x32_bf16(af1, bf1, acc[1][1], 0, 0, 0);
    }
    __syncthreads();
    buf ^= 1;
  }

  const float* barr = (ncg == 0) ? b3 : (ncg == 1) ? b5 : b7;
#pragma unroll
  for (int j = 0; j < 2; ++j) {
    int fcol = nh * 64 + wn * 32 + 16 * j + l15;
    float bias = barr[fcol];
    float mpl = -NEG_INF_F, mpr = -NEG_INF_F;
#pragma unroll
    for (int i = 0; i < 2; ++i) {
#pragma unroll
      for (int r = 0; r < 4; ++r) {
        int rl = wm * 32 + 16 * i + 4 * kg + r;
        float cva = fmaxf(acc[i][j][r] + bias, 0.f);
        float ml = sml[rl], mr = smr[rl];
        mpl = fmaxf(mpl, cva * ml - (1.f - ml) * NEG_INF_F);
        mpr = fmaxf(mpr, cva * mr - (1.f - mr) * NEG_INF_F);
      }
    }
    mpl = fmaxf(mpl, __shfl_xor(mpl, 16));
    mpl = fmaxf(mpl, __shfl_xor(mpl, 32));
    mpr = fmaxf(mpr, __shfl_xor(mpr, 16));
    mpr = fmaxf(mpr, __shfl_xor(mpr, 32));
    if (ln < 16) {
      atomicMax((int*)&ctxpool[(size_t)b * CTX_DIM + ncg * 128 + fcol],
                __float_as_int(mpl));
      atomicMax((int*)&ctxpool[(size_t)b * CTX_DIM + 384 + ncg * 128 + fcol],
                __float_as_int(mpr));
    }
  }
}

// ---------------------------------------------------------------------------
// K3: scorer GEMM (mt<40) + noise ctx-part (mt 40..41 -> hctxn). As staged
// with 16B-slot XOR swizzle (write+read both ds ops) -> ~2-way banks.
__global__ __launch_bounds__(256) void k_mlp(
    const float* __restrict__ ctxp, const __hip_bfloat16* __restrict__ candb,
    const __hip_bfloat16* __restrict__ W1br, const float* __restrict__ sb1,
    const float* __restrict__ sW2, float* __restrict__ part,
    float* __restrict__ hctxn) {
  int mt = blockIdx.x;
  bool noise = (mt >= 40);
  int w = threadIdx.x >> 6;
  int sub = blockIdx.y * 4 + w;
  int lane = threadIdx.x & 63;
  int lrow = lane & 31, kg2 = lane >> 5;
  __shared__ __align__(16) __hip_bfloat16 As[32 * 904];

  {
    int row = threadIdx.x >> 3, seg = threadIdx.x & 7;
    int xr = (row >> 1) & 7;
    if (!noise) {
      int m = mt * 32 + row;
      int bb = m / 20;
      const float* cp = ctxp + (size_t)bb * CTX_DIM;
#pragma unroll
      for (int q = 0; q < 14; ++q) {
        int k = seg * 112 + q * 8;
        bf16x8 v;
        if (k < CTX_DIM)
          v = cvt8(*(const float4*)(cp + k), *(const float4*)(cp + k + 4));
        else
          v = *(const bf16x8*)&candb[(size_t)m * EDIM + (k - CTX_DIM)];
        *(bf16x8*)&As[row * 904 + (((k >> 3) ^ xr) << 3)] = v;
      }
    } else {
      int bb = (mt - 40) * 32 + row;
      const float* cp = ctxp + (size_t)bb * CTX_DIM;
#pragma unroll
      for (int q = 0; q < 14; ++q) {
        int k = seg * 112 + q * 8;
        if (k < CTX_DIM)
          *(bf16x8*)&As[row * 904 + (((k >> 3) ^ xr) << 3)] =
              cvt8(*(const float4*)(cp + k), *(const float4*)(cp + k + 4));
      }
    }
  }
  __syncthreads();

  int xrr = (lrow >> 1) & 7;
  f32x16 acc = {};
  if (!noise) {
    const __hip_bfloat16* W1b = W1br;
#pragma unroll 4
    for (int k0 = 0; k0 < 56; ++k0) {
      int s16 = k0 * 2 + kg2;
      bf16x8 av = *(const bf16x8*)&As[lrow * 904 + ((s16 ^ xrr) << 3)];
      bf16x8 bv = *(const bf16x8*)&W1b[((size_t)sub * 56 + k0) * 512 +
                                       lrow * 16 + kg2 * 8];
      acc = __builtin_amdgcn_mfma_f32_32x32x16_bf16(av, bv, acc, 0, 0, 0);
    }
    int n = sub * 32 + lrow;
    float b1n = sb1[n], w2n = sW2[n];
#pragma unroll
    for (int r = 0; r < 16; ++r) {
      float v = fmaxf(acc[r] + b1n, 0.f) * w2n;
#pragma unroll
      for (int off = 16; off; off >>= 1) v += __shfl_xor(v, off);
      if (lrow == 0) {
        int mm = mt * 32 + (r & 3) + 8 * (r >> 2) + 4 * kg2;
        part[(size_t)sub * (B * N_CANDS) + mm] = v;
      }
    }
  } else {
    const __hip_bfloat16* W1b = W1br + (size_t)(16 * 56 * 512);
#pragma unroll 4
    for (int k0 = 0; k0 < 48; ++k0) {
      int s16 = k0 * 2 + kg2;
      bf16x8 av = *(const bf16x8*)&As[lrow * 904 + ((s16 ^ xrr) << 3)];
      bf16x8 bv = *(const bf16x8*)&W1b[((size_t)sub * 56 + k0) * 512 +
                                       lrow * 16 + kg2 * 8];
      acc = __builtin_amdgcn_mfma_f32_32x32x16_bf16(av, bv, acc, 0, 0, 0);
    }
#pragma unroll
    for (int r = 0; r < 16; ++r) {
      int mrow = (r & 3) + 8 * (r >> 2) + 4 * kg2;
      hctxn[(size_t)((mt - 40) * 32 + mrow) * EN_DIM + sub * 32 + lrow] =
          acc[r];
    }
  }
}

// ---------------------------------------------------------------------------
// K4 tail: one block per batch row (64 blocks x 256). Scores finish+write,
// softmax(10), e (f32), vector noise head on f32 nW1 rows 768..895.
__global__ __launch_bounds__(256) void k_tail(
    const float* __restrict__ part, const __hip_bfloat16* __restrict__ candb,
    const float* __restrict__ hctxn, const int* __restrict__ real_n_poss,
    const float* __restrict__ sb2, const float* __restrict__ nW1,
    const float* __restrict__ nb1, const float* __restrict__ nW2,
    const float* __restrict__ nb2, float* __restrict__ out) {
  int b = blockIdx.x, tid = threadIdx.x;
  __shared__ float ssc[N_CANDS];
  __shared__ float sp[N_POSS];
  __shared__ float e_sh[EDIM];
  __shared__ float red[4];

  if (tid < N_CANDS) {
    int m = b * N_CANDS + tid;
    float s = sb2[0];
#pragma unroll
    for (int p = 0; p < 16; ++p) s += part[(size_t)p * (B * N_CANDS) + m];
    if (tid < N_POSS && (tid + 1) > real_n_poss[b]) s = -NEG_INF_F;
    ssc[tid] = s;
    out[m] = s;
  }
  __syncthreads();
  if (tid == 0) {
    float mx = -INFINITY;
#pragma unroll
    for (int c = 0; c < N_POSS; ++c) mx = fmaxf(mx, ssc[c]);
    float ssum = 0.f;
    float pe[N_POSS];
#pragma unroll
    for (int c = 0; c < N_POSS; ++c) {
      pe[c] = expf(ssc[c] - mx);
      ssum += pe[c];
    }
    float inv = 1.f / ssum;
#pragma unroll
    for (int c = 0; c < N_POSS; ++c) sp[c] = pe[c] * inv;
  }
  __syncthreads();
  if (tid < EDIM) {
    float ev = 0.f;
#pragma unroll
    for (int c = 0; c < N_POSS; ++c)
      ev = fmaf(sp[c],
                __bfloat162float(candb[(size_t)(b * N_CANDS + c) * EDIM + tid]),
                ev);
    e_sh[tid] = ev;
  }
  __syncthreads();

  // noise hidden: n = tid and tid+256
  float h0 = nb1[tid] + hctxn[(size_t)b * EN_DIM + tid];
  float h1 = nb1[tid + 256] + hctxn[(size_t)b * EN_DIM + tid + 256];
#pragma unroll 4
  for (int k = 0; k < EDIM; ++k) {
    float ek = e_sh[k];
    const float* wr = nW1 + (size_t)(CTX_DIM + k) * EN_DIM;
    h0 = fmaf(ek, wr[tid], h0);
    h1 = fmaf(ek, wr[tid + 256], h1);
  }
  float v = fmaxf(h0, 0.f) * nW2[tid] + fmaxf(h1, 0.f) * nW2[tid + 256];
#pragma unroll
  for (int off = 32; off; off >>= 1) v += __shfl_xor(v, off);
  if ((tid & 63) == 0) red[tid >> 6] = v;
  __syncthreads();
  if (tid == 0)
    out[B * N_CANDS + b] = red[0] + red[1] + red[2] + red[3] + nb2[0];
}

// ---------------------------------------------------------------------------
extern "C" void kernel_launch(void* const* d_in, const int* in_sizes, int n_in,
                              void* d_out, int out_size, void* d_ws,
                              size_t ws_size, hipStream_t stream) {
  const int* tokens = (const int*)d_in[0];
  const int* pos = (const int*)d_in[1];
  const float* masks = (const float*)d_in[2];
  const int* nb_types = (const int*)d_in[3];
  const int* nb_n_types = (const int*)d_in[5];
  const int* nb_rs = (const int*)d_in[6];
  const int* real_n_poss = (const int*)d_in[8];
  const float* word_embs = (const float*)d_in[10];
  const float* pos_emb = (const float*)d_in[11];
  const float* type_emb = (const float*)d_in[12];
  const float* rel_emb = (const float*)d_in[13];
  const float* rel_weight = (const float*)d_in[14];
  const float* w3 = (const float*)d_in[15];
  const float* b3 = (const float*)d_in[16];
  const float* w5 = (const float*)d_in[17];
  const float* b5 = (const float*)d_in[18];
  const float* w7 = (const float*)d_in[19];
  const float* b7 = (const float*)d_in[20];
  const float* sW1 = (const float*)d_in[21];
  const float* sb1 = (const float*)d_in[22];
  const float* sW2 = (const float*)d_in[23];
  const float* sb2 = (const float*)d_in[24];
  const float* nW1 = (const float*)d_in[25];
  const float* nb1 = (const float*)d_in[26];
  const float* nW2 = (const float*)d_in[27];
  const float* nb2 = (const float*)d_in[28];

  __hip_bfloat16* Xbr = (__hip_bfloat16*)d_ws;          // 3,244,032 bf16
  __hip_bfloat16* Wbr = Xbr + (size_t)3244032;          //   946,176
  __hip_bfloat16* W1br = Wbr + (size_t)946176;          //   917,504
  __hip_bfloat16* candb = W1br + (size_t)917504;        //   163,840
  float* ctxpool = (float*)(candb + (size_t)163840);    //    49,152 f32
  float* part = ctxpool + (size_t)B * CTX_DIM;          //    20,480 f32
  float* hctxn = part + (size_t)16 * B * N_CANDS;       //    32,768 f32
  float* out = (float*)d_out;

  hipLaunchKernelGGL(k_front, dim3(2743), dim3(256), 0, stream, nb_types,
                     nb_n_types, nb_rs, type_emb, rel_emb, rel_weight, candb,
                     tokens, pos, word_embs, pos_emb, Xbr, w3, w5, w7, Wbr,
                     sW1, nW1, W1br, ctxpool);
  hipLaunchKernelGGL(k_conv, dim3(B, 2, 6), dim3(256), 0, stream, Xbr, Wbr,
                     pos, masks, b3, b5, b7, ctxpool);
  hipLaunchKernelGGL(k_mlp, dim3(42, 4), dim3(256), 0, stream, ctxpool, candb,
                     W1br, sb1, sW2, part, hctxn);
  hipLaunchKernelGGL(k_tail, dim3(B), dim3(256), 0, stream, part, candb,
                     hctxn, real_n_poss, sb2, nW1, nb1, nW2, nb2, out);
}

// Round 8
// 94.966 us; speedup vs baseline: 1.6275x; 1.1531x over previous
//
#include <hip/hip_runtime.h>
#include <hip/hip_bf16.h>

#define B 64
#define L 100
#define WDIM 300
#define PDIM 50
#define DIM 350
#define NK0 11              // 352/32 k-chunks
#define BRICK_ROWS 144      // rows per (b,k0) brick; row r -> l' = r-3
#define NSHIFT 7
#define NKK 77              // 11 k0 * 7 shifts
#define N_CANDS 20
#define N_POSS 10
#define NB_PER_CAND 64
#define TDIM 128
#define EDIM 128
#define CTX_DIM 768
#define EN_HID1 896
#define EN_DIM 512
#define NEG_INF_F 1.0e10f

typedef __attribute__((ext_vector_type(8))) short bf16x8;
typedef __attribute__((ext_vector_type(4))) float f32x4;
typedef __attribute__((ext_vector_type(16))) float f32x16;

__device__ __forceinline__ void gload_lds16(const __hip_bfloat16* g,
                                            __hip_bfloat16* l) {
  __builtin_amdgcn_global_load_lds(
      (const __attribute__((address_space(1))) unsigned int*)(g),
      (__attribute__((address_space(3))) unsigned int*)(l), 16, 0, 0);
}

__device__ __forceinline__ bf16x8 cvt8(float4 a, float4 b) {
  union { bf16x8 v; __hip_bfloat16 h[8]; } u;
  u.h[0] = __float2bfloat16(a.x); u.h[1] = __float2bfloat16(a.y);
  u.h[2] = __float2bfloat16(a.z); u.h[3] = __float2bfloat16(a.w);
  u.h[4] = __float2bfloat16(b.x); u.h[5] = __float2bfloat16(b.y);
  u.h[6] = __float2bfloat16(b.z); u.h[7] = __float2bfloat16(b.w);
  return u.v;
}

// ---------------------------------------------------------------------------
// K1 k_front (fused): [0,1280) cand; [1280,2432) Xbr (pre-swizzled);
// [2432,2663) Wbr; [2663,2919) W1br (LDS tile transpose, coalesced);
// [2919,2967) ctxpool init.
__global__ __launch_bounds__(256) void k_front(
    const int* __restrict__ nb_types, const int* __restrict__ nb_n_types,
    const int* __restrict__ nb_rs, const float* __restrict__ type_emb,
    const float* __restrict__ rel_emb, const float* __restrict__ rel_weight,
    __hip_bfloat16* __restrict__ candb, const int* __restrict__ tokens,
    const int* __restrict__ pos, const float* __restrict__ word_embs,
    const float* __restrict__ pos_emb, __hip_bfloat16* __restrict__ Xbr,
    const float* __restrict__ w3, const float* __restrict__ w5,
    const float* __restrict__ w7, __hip_bfloat16* __restrict__ Wbr,
    const float* __restrict__ sW1, const float* __restrict__ nW1,
    __hip_bfloat16* __restrict__ W1br, float* __restrict__ ctxpool) {
  int blk = blockIdx.x, tid = threadIdx.x;
  __shared__ int sty[NB_PER_CAND * 4];
  __shared__ int srs[NB_PER_CAND];
  __shared__ float sinv[NB_PER_CAND];
  __shared__ float pS[2][128], pR[2][128], sS[128];
  __shared__ float tile[112][33];

  if (blk < 1280) {  // ---- cand (f32 tables)
    int c = blk;
    int g = tid >> 7, d = tid & 127;
    sty[tid] = nb_types[c * NB_PER_CAND * 4 + tid];
    if (tid < NB_PER_CAND) {
      srs[tid] = nb_rs[c * NB_PER_CAND + tid];
      sinv[tid] = 1.f / (float)nb_n_types[c * NB_PER_CAND + tid];
    }
    __syncthreads();
    float accS = 0.f, accR = 0.f;
#pragma unroll 4
    for (int j2 = 0; j2 < 32; ++j2) {
      int j = g * 32 + j2;
      accR += rel_emb[srs[j] * EDIM + d];
      float s4 = 0.f;
#pragma unroll
      for (int k = 0; k < 4; ++k) s4 += type_emb[sty[j * 4 + k] * TDIM + d];
      accS = fmaf(s4, sinv[j], accS);
    }
    pS[g][d] = accS;
    pR[g][d] = accR;
    __syncthreads();
    if (tid < 128) sS[d] = pS[0][d] + pS[1][d];
    __syncthreads();
    float dotp = (g == 0) ? (pR[0][d] + pR[1][d]) : 0.f;
#pragma unroll 4
    for (int k2 = 0; k2 < 64; ++k2) {
      int k = g * 64 + k2;
      dotp = fmaf(sS[k], rel_weight[k * EDIM + d], dotp);
    }
    pS[g][d] = dotp;
    __syncthreads();
    if (tid < 128)
      candb[(size_t)c * EDIM + d] =
          __float2bfloat16(fmaxf(pS[0][d] + pS[1][d], 0.f));
  } else if (blk < 2432) {  // ---- Xbr bricks (swizzled)
    int idx = blk - 1280;
    int b = idx / 18, r0 = (idx % 18) * 8;
    __hip_bfloat16* base = Xbr + (size_t)b * (NK0 * BRICK_ROWS * 32);
    for (int r = r0; r < r0 + 8; ++r) {
      int lp = r - 3;
      int xr = (r >> 1) & 3;
      if (lp >= 0 && lp < L) {
        int tok = tokens[b * L + lp];
        int pp = pos[b * L + lp] + 100;
        const float* wrow = word_embs + (size_t)tok * WDIM;
        const float* prow = pos_emb + (size_t)pp * PDIM;
        for (int d = tid; d < 352; d += 256) {
          float v = (d < WDIM) ? wrow[d] : (d < DIM) ? prow[d - WDIM] : 0.f;
          int slot = (d >> 3) & 3;
          base[((size_t)(d >> 5) * BRICK_ROWS + r) * 32 +
               ((slot ^ xr) << 3) + (d & 7)] = __float2bfloat16(v);
        }
      } else {
        for (int d = tid; d < 352; d += 256) {
          int slot = (d >> 3) & 3;
          base[((size_t)(d >> 5) * BRICK_ROWS + r) * 32 +
               ((slot ^ xr) << 3) + (d & 7)] = __float2bfloat16(0.f);
        }
      }
    }
  } else if (blk < 2663) {  // ---- Wbr bricks
    int idx = blk - 2432;
    int ncg = idx / NKK, kkb = idx % NKK;
    if (tid < 128) {
      int k0 = kkb / NSHIFT, s = kkb - NSHIFT * k0;
      int col = tid;
      const float* w = (ncg == 0) ? w3 : (ncg == 1) ? w5 : w7;
      int fs = (ncg == 0) ? 3 : (ncg == 1) ? 5 : 7;
      int dl = (ncg == 0) ? s - 2 : (ncg == 1) ? s - 1 : s;
      bool valid = (dl >= 0 && dl < fs);
      __hip_bfloat16* dst = Wbr + (((size_t)ncg * NKK + kkb) * 128 + col) * 32;
      for (int k = 0; k < 32; ++k) {
        int d = k0 * 32 + k;
        float v =
            (valid && d < DIM) ? w[((size_t)col * fs + dl) * DIM + d] : 0.f;
        dst[k] = __float2bfloat16(v);
      }
    }
  } else if (blk < 2919) {  // ---- W1br via LDS tile transpose (coalesced)
    int idx = blk - 2663;            // 0..255
    int which = idx >> 7;            // 0..1
    int rem = idx & 127;
    int sub = rem >> 3;              // 0..15
    int kc = rem & 7;                // 0..7 (112 k each)
    const float* src = which ? nW1 : sW1;
    __hip_bfloat16* dst = W1br + (size_t)which * (16 * 56 * 512);
    for (int i = tid; i < 112 * 32; i += 256) {
      int kk = i >> 5, col = i & 31;
      tile[kk][col] = src[(size_t)(kc * 112 + kk) * EN_DIM + sub * 32 + col];
    }
    __syncthreads();
    for (int i = tid; i < 32 * 112; i += 256) {
      int col = i / 112, kk = i - col * 112;
      int k = kc * 112 + kk;
      dst[((size_t)(sub * 56 + (k >> 4)) * 32 + col) * 16 + (k & 15)] =
          __float2bfloat16(tile[kk][col]);
    }
  } else {  // ---- ctxpool init
    int idx = blk - 2919;
    int i0 = idx * 1024 + tid * 4;
#pragma unroll
    for (int q = 0; q < 4; ++q) ctxpool[i0 + q] = -NEG_INF_F;
  }
}

// ---------------------------------------------------------------------------
// K2 conv: 11 barrier-steps; per-ncg ONLY the real taps (3/5/7) are computed
// (skips the zero-padded shifts: 29% less MFMA+B-traffic). A staged via
// global_load_lds from pre-swizzled Xbr; B direct from L2-resident Wbr.
__global__ __launch_bounds__(256) void k_conv(
    const __hip_bfloat16* __restrict__ Xbr,
    const __hip_bfloat16* __restrict__ Wbr, const int* __restrict__ pos,
    const float* __restrict__ masks, const float* __restrict__ b3,
    const float* __restrict__ b5, const float* __restrict__ b7,
    float* __restrict__ ctxpool) {
  int b = blockIdx.x;
  int mt = blockIdx.y;  // 0..1
  int nt = blockIdx.z;  // 0..5
  int ncg = nt >> 1, nh = nt & 1;
  int slo = 2 - ncg, shi = 4 + ncg;  // valid taps: 3 / 5 / 7
  int tid = threadIdx.x;
  int wv = tid >> 6, ln = tid & 63;
  int wm = wv >> 1, wn = wv & 1;
  int l15 = ln & 15, kg = ln >> 4;

  __shared__ __align__(16) __hip_bfloat16 Asb[2][80 * 32];
  __shared__ float sml[64], smr[64];

  if (tid < 64) {
    int l = mt * 64 + tid;
    float mlv = 0.f, mrv = 0.f;
    if (l < L) {
      int p = pos[b * L + l];
      mlv = (p <= 0) ? 1.f : 0.f;
      mrv = (p >= 0) ? masks[b * L + l] : 0.f;
    }
    sml[tid] = mlv;
    smr[tid] = mrv;
  }

  const __hip_bfloat16* XB =
      Xbr + (size_t)b * (NK0 * BRICK_ROWS * 32) + (size_t)mt * 64 * 32;
  const __hip_bfloat16* WBl =
      Wbr + ((size_t)ncg * NKK * 128 + nh * 64 + wn * 32 + l15) * 32 + kg * 8;

  for (int seg = wv; seg < 5; seg += 4)
    gload_lds16(XB + (seg * 64 + ln) * 8, &Asb[0][(seg * 64 + ln) * 8]);
  __syncthreads();

  f32x4 acc[2][2];
#pragma unroll
  for (int i = 0; i < 2; ++i)
#pragma unroll
    for (int j = 0; j < 2; ++j) acc[i][j] = (f32x4){0.f, 0.f, 0.f, 0.f};

  int buf = 0;
  for (int k0 = 0; k0 < NK0; ++k0) {
    if (k0 < NK0 - 1) {
      const __hip_bfloat16* asrc = XB + (size_t)(k0 + 1) * (BRICK_ROWS * 32);
      for (int seg = wv; seg < 5; seg += 4)
        gload_lds16(asrc + (seg * 64 + ln) * 8,
                    &Asb[buf ^ 1][(seg * 64 + ln) * 8]);
    }
#pragma unroll
    for (int s = 0; s < NSHIFT; ++s) {
      if (s < slo || s > shi) continue;  // block-uniform: skip zero taps
      const __hip_bfloat16* bp = WBl + (size_t)(k0 * NSHIFT + s) * 4096;
      bf16x8 bf0 = *(const bf16x8*)(bp);
      bf16x8 bf1 = *(const bf16x8*)(bp + 512);
      int rbase = wm * 32 + l15 + s;
      int xr = (kg ^ ((rbase >> 1) & 3)) << 3;
      bf16x8 af0 = *(const bf16x8*)&Asb[buf][rbase * 32 + xr];
      bf16x8 af1 = *(const bf16x8*)&Asb[buf][(rbase + 16) * 32 + xr];
      acc[0][0] = __builtin_amdgcn_mfma_f32_16x16x32_bf16(af0, bf0, acc[0][0], 0, 0, 0);
      acc[0][1] = __builtin_amdgcn_mfma_f32_16x16x32_bf16(af0, bf1, acc[0][1], 0, 0, 0);
      acc[1][0] = __builtin_amdgcn_mfma_f32_16x16x32_bf16(af1, bf0, acc[1][0], 0, 0, 0);
      acc[1][1] = __builtin_amdgcn_mfma_f32_16x16x32_bf16(af1, bf1, acc[1][1], 0, 0, 0);
    }
    __syncthreads();
    buf ^= 1;
  }

  const float* barr = (ncg == 0) ? b3 : (ncg == 1) ? b5 : b7;
#pragma unroll
  for (int j = 0; j < 2; ++j) {
    int fcol = nh * 64 + wn * 32 + 16 * j + l15;
    float bias = barr[fcol];
    float mpl = -NEG_INF_F, mpr = -NEG_INF_F;
#pragma unroll
    for (int i = 0; i < 2; ++i) {
#pragma unroll
      for (int r = 0; r < 4; ++r) {
        int rl = wm * 32 + 16 * i + 4 * kg + r;
        float cva = fmaxf(acc[i][j][r] + bias, 0.f);
        float ml = sml[rl], mr = smr[rl];
        mpl = fmaxf(mpl, cva * ml - (1.f - ml) * NEG_INF_F);
        mpr = fmaxf(mpr, cva * mr - (1.f - mr) * NEG_INF_F);
      }
    }
    mpl = fmaxf(mpl, __shfl_xor(mpl, 16));
    mpl = fmaxf(mpl, __shfl_xor(mpl, 32));
    mpr = fmaxf(mpr, __shfl_xor(mpr, 16));
    mpr = fmaxf(mpr, __shfl_xor(mpr, 32));
    if (ln < 16) {
      atomicMax((int*)&ctxpool[(size_t)b * CTX_DIM + ncg * 128 + fcol],
                __float_as_int(mpl));
      atomicMax((int*)&ctxpool[(size_t)b * CTX_DIM + 384 + ncg * 128 + fcol],
                __float_as_int(mpr));
    }
  }
}

// ---------------------------------------------------------------------------
// K3: scorer GEMM (mt<40) + noise ctx-part (mt 40..41 -> hctxn).
// Grid (42, 8) x 128 threads (2 waves, 2 subs) for >256 blocks. As staged
// with 16B-slot XOR swizzle (write+read both ds ops).
__global__ __launch_bounds__(128) void k_mlp(
    const float* __restrict__ ctxp, const __hip_bfloat16* __restrict__ candb,
    const __hip_bfloat16* __restrict__ W1br, const float* __restrict__ sb1,
    const float* __restrict__ sW2, float* __restrict__ part,
    float* __restrict__ hctxn) {
  int mt = blockIdx.x;
  bool noise = (mt >= 40);
  int w = threadIdx.x >> 6;
  int sub = blockIdx.y * 2 + w;
  int lane = threadIdx.x & 63;
  int lrow = lane & 31, kg2 = lane >> 5;
  __shared__ __align__(16) __hip_bfloat16 As[32 * 904];

  {
    int row = threadIdx.x >> 2, seg = threadIdx.x & 3;
    int xr = (row >> 1) & 7;
    if (!noise) {
      int m = mt * 32 + row;
      int bb = m / 20;
      const float* cp = ctxp + (size_t)bb * CTX_DIM;
#pragma unroll
      for (int q = 0; q < 28; ++q) {
        int k = seg * 224 + q * 8;
        bf16x8 v;
        if (k < CTX_DIM)
          v = cvt8(*(const float4*)(cp + k), *(const float4*)(cp + k + 4));
        else
          v = *(const bf16x8*)&candb[(size_t)m * EDIM + (k - CTX_DIM)];
        *(bf16x8*)&As[row * 904 + (((k >> 3) ^ xr) << 3)] = v;
      }
    } else {
      int bb = (mt - 40) * 32 + row;
      const float* cp = ctxp + (size_t)bb * CTX_DIM;
#pragma unroll
      for (int q = 0; q < 28; ++q) {
        int k = seg * 224 + q * 8;
        if (k < CTX_DIM)
          *(bf16x8*)&As[row * 904 + (((k >> 3) ^ xr) << 3)] =
              cvt8(*(const float4*)(cp + k), *(const float4*)(cp + k + 4));
      }
    }
  }
  __syncthreads();

  int xrr = (lrow >> 1) & 7;
  f32x16 acc = {};
  if (!noise) {
    const __hip_bfloat16* W1b = W1br;
#pragma unroll 4
    for (int k0 = 0; k0 < 56; ++k0) {
      int s16 = k0 * 2 + kg2;
      bf16x8 av = *(const bf16x8*)&As[lrow * 904 + ((s16 ^ xrr) << 3)];
      bf16x8 bv = *(const bf16x8*)&W1b[((size_t)sub * 56 + k0) * 512 +
                                       lrow * 16 + kg2 * 8];
      acc = __builtin_amdgcn_mfma_f32_32x32x16_bf16(av, bv, acc, 0, 0, 0);
    }
    int n = sub * 32 + lrow;
    float b1n = sb1[n], w2n = sW2[n];
#pragma unroll
    for (int r = 0; r < 16; ++r) {
      float v = fmaxf(acc[r] + b1n, 0.f) * w2n;
#pragma unroll
      for (int off = 16; off; off >>= 1) v += __shfl_xor(v, off);
      if (lrow == 0) {
        int mm = mt * 32 + (r & 3) + 8 * (r >> 2) + 4 * kg2;
        part[(size_t)sub * (B * N_CANDS) + mm] = v;
      }
    }
  } else {
    const __hip_bfloat16* W1b = W1br + (size_t)(16 * 56 * 512);
#pragma unroll 4
    for (int k0 = 0; k0 < 48; ++k0) {
      int s16 = k0 * 2 + kg2;
      bf16x8 av = *(const bf16x8*)&As[lrow * 904 + ((s16 ^ xrr) << 3)];
      bf16x8 bv = *(const bf16x8*)&W1b[((size_t)sub * 56 + k0) * 512 +
                                       lrow * 16 + kg2 * 8];
      acc = __builtin_amdgcn_mfma_f32_32x32x16_bf16(av, bv, acc, 0, 0, 0);
    }
#pragma unroll
    for (int r = 0; r < 16; ++r) {
      int mrow = (r & 3) + 8 * (r >> 2) + 4 * kg2;
      hctxn[(size_t)((mt - 40) * 32 + mrow) * EN_DIM + sub * 32 + lrow] =
          acc[r];
    }
  }
}

// ---------------------------------------------------------------------------
// K4 tail: one block per batch row (64 x 256). Scores finish+write,
// softmax(10), e (f32), vector noise head on f32 nW1 rows 768..895.
__global__ __launch_bounds__(256) void k_tail(
    const float* __restrict__ part, const __hip_bfloat16* __restrict__ candb,
    const float* __restrict__ hctxn, const int* __restrict__ real_n_poss,
    const float* __restrict__ sb2, const float* __restrict__ nW1,
    const float* __restrict__ nb1, const float* __restrict__ nW2,
    const float* __restrict__ nb2, float* __restrict__ out) {
  int b = blockIdx.x, tid = threadIdx.x;
  __shared__ float ssc[N_CANDS];
  __shared__ float sp[N_POSS];
  __shared__ float e_sh[EDIM];
  __shared__ float red[4];

  if (tid < N_CANDS) {
    int m = b * N_CANDS + tid;
    float s = sb2[0];
#pragma unroll
    for (int p = 0; p < 16; ++p) s += part[(size_t)p * (B * N_CANDS) + m];
    if (tid < N_POSS && (tid + 1) > real_n_poss[b]) s = -NEG_INF_F;
    ssc[tid] = s;
    out[m] = s;
  }
  __syncthreads();
  if (tid == 0) {
    float mx = -INFINITY;
#pragma unroll
    for (int c = 0; c < N_POSS; ++c) mx = fmaxf(mx, ssc[c]);
    float ssum = 0.f;
    float pe[N_POSS];
#pragma unroll
    for (int c = 0; c < N_POSS; ++c) {
      pe[c] = expf(ssc[c] - mx);
      ssum += pe[c];
    }
    float inv = 1.f / ssum;
#pragma unroll
    for (int c = 0; c < N_POSS; ++c) sp[c] = pe[c] * inv;
  }
  __syncthreads();
  if (tid < EDIM) {
    float ev = 0.f;
#pragma unroll
    for (int c = 0; c < N_POSS; ++c)
      ev = fmaf(sp[c],
                __bfloat162float(candb[(size_t)(b * N_CANDS + c) * EDIM + tid]),
                ev);
    e_sh[tid] = ev;
  }
  __syncthreads();

  float h0 = nb1[tid] + hctxn[(size_t)b * EN_DIM + tid];
  float h1 = nb1[tid + 256] + hctxn[(size_t)b * EN_DIM + tid + 256];
#pragma unroll 4
  for (int k = 0; k < EDIM; ++k) {
    float ek = e_sh[k];
    const float* wr = nW1 + (size_t)(CTX_DIM + k) * EN_DIM;
    h0 = fmaf(ek, wr[tid], h0);
    h1 = fmaf(ek, wr[tid + 256], h1);
  }
  float v = fmaxf(h0, 0.f) * nW2[tid] + fmaxf(h1, 0.f) * nW2[tid + 256];
#pragma unroll
  for (int off = 32; off; off >>= 1) v += __shfl_xor(v, off);
  if ((tid & 63) == 0) red[tid >> 6] = v;
  __syncthreads();
  if (tid == 0)
    out[B * N_CANDS + b] = red[0] + red[1] + red[2] + red[3] + nb2[0];
}

// ---------------------------------------------------------------------------
extern "C" void kernel_launch(void* const* d_in, const int* in_sizes, int n_in,
                              void* d_out, int out_size, void* d_ws,
                              size_t ws_size, hipStream_t stream) {
  const int* tokens = (const int*)d_in[0];
  const int* pos = (const int*)d_in[1];
  const float* masks = (const float*)d_in[2];
  const int* nb_types = (const int*)d_in[3];
  const int* nb_n_types = (const int*)d_in[5];
  const int* nb_rs = (const int*)d_in[6];
  const int* real_n_poss = (const int*)d_in[8];
  const float* word_embs = (const float*)d_in[10];
  const float* pos_emb = (const float*)d_in[11];
  const float* type_emb = (const float*)d_in[12];
  const float* rel_emb = (const float*)d_in[13];
  const float* rel_weight = (const float*)d_in[14];
  const float* w3 = (const float*)d_in[15];
  const float* b3 = (const float*)d_in[16];
  const float* w5 = (const float*)d_in[17];
  const float* b5 = (const float*)d_in[18];
  const float* w7 = (const float*)d_in[19];
  const float* b7 = (const float*)d_in[20];
  const float* sW1 = (const float*)d_in[21];
  const float* sb1 = (const float*)d_in[22];
  const float* sW2 = (const float*)d_in[23];
  const float* sb2 = (const float*)d_in[24];
  const float* nW1 = (const float*)d_in[25];
  const float* nb1 = (const float*)d_in[26];
  const float* nW2 = (const float*)d_in[27];
  const float* nb2 = (const float*)d_in[28];

  __hip_bfloat16* Xbr = (__hip_bfloat16*)d_ws;          // 3,244,032 bf16
  __hip_bfloat16* Wbr = Xbr + (size_t)3244032;          //   946,176
  __hip_bfloat16* W1br = Wbr + (size_t)946176;          //   917,504
  __hip_bfloat16* candb = W1br + (size_t)917504;        //   163,840
  float* ctxpool = (float*)(candb + (size_t)163840);    //    49,152 f32
  float* part = ctxpool + (size_t)B * CTX_DIM;          //    20,480 f32
  float* hctxn = part + (size_t)16 * B * N_CANDS;       //    32,768 f32
  float* out = (float*)d_out;

  hipLaunchKernelGGL(k_front, dim3(2967), dim3(256), 0, stream, nb_types,
                     nb_n_types, nb_rs, type_emb, rel_emb, rel_weight, candb,
                     tokens, pos, word_embs, pos_emb, Xbr, w3, w5, w7, Wbr,
                     sW1, nW1, W1br, ctxpool);
  hipLaunchKernelGGL(k_conv, dim3(B, 2, 6), dim3(256), 0, stream, Xbr, Wbr,
                     pos, masks, b3, b5, b7, ctxpool);
  hipLaunchKernelGGL(k_mlp, dim3(42, 8), dim3(128), 0, stream, ctxpool, candb,
                     W1br, sb1, sW2, part, hctxn);
  hipLaunchKernelGGL(k_tail, dim3(B), dim3(256), 0, stream, part, candb,
                     hctxn, real_n_poss, sb2, nW1, nb1, nW2, nb2, out);
}

// Round 9
// 84.408 us; speedup vs baseline: 1.8311x; 1.1251x over previous
//
#include <hip/hip_runtime.h>
#include <hip/hip_bf16.h>

#define B 64
#define L 100
#define WDIM 300
#define PDIM 50
#define DIM 350
#define NK0 11              // 352/32 k-chunks
#define BRICK_ROWS 144      // rows per (b,k0) brick; row r -> l' = r-3
#define NSHIFT 7
#define NKK 77              // 11 k0 * 7 shifts
#define N_CANDS 20
#define N_POSS 10
#define NB_PER_CAND 64
#define TDIM 128
#define EDIM 128
#define CTX_DIM 768
#define EN_HID1 896
#define EN_DIM 512
#define NEG_INF_F 1.0e10f

typedef __attribute__((ext_vector_type(8))) short bf16x8;
typedef __attribute__((ext_vector_type(4))) float f32x4;
typedef __attribute__((ext_vector_type(16))) float f32x16;

__device__ __forceinline__ void gload_lds16(const __hip_bfloat16* g,
                                            __hip_bfloat16* l) {
  __builtin_amdgcn_global_load_lds(
      (const __attribute__((address_space(1))) unsigned int*)(g),
      (__attribute__((address_space(3))) unsigned int*)(l), 16, 0, 0);
}

__device__ __forceinline__ bf16x8 cvt8(float4 a, float4 b) {
  union { bf16x8 v; __hip_bfloat16 h[8]; } u;
  u.h[0] = __float2bfloat16(a.x); u.h[1] = __float2bfloat16(a.y);
  u.h[2] = __float2bfloat16(a.z); u.h[3] = __float2bfloat16(a.w);
  u.h[4] = __float2bfloat16(b.x); u.h[5] = __float2bfloat16(b.y);
  u.h[6] = __float2bfloat16(b.z); u.h[7] = __float2bfloat16(b.w);
  return u.v;
}

// ---------------------------------------------------------------------------
// K1 k_front: ONLY what conv needs. [0,1152) Xbr (pre-swizzled);
// [1152,1383) Wbr; [1383,1431) ctxpool init.
__global__ __launch_bounds__(256) void k_front(
    const int* __restrict__ tokens, const int* __restrict__ pos,
    const float* __restrict__ word_embs, const float* __restrict__ pos_emb,
    __hip_bfloat16* __restrict__ Xbr, const float* __restrict__ w3,
    const float* __restrict__ w5, const float* __restrict__ w7,
    __hip_bfloat16* __restrict__ Wbr, float* __restrict__ ctxpool) {
  int blk = blockIdx.x, tid = threadIdx.x;
  if (blk < 1152) {  // ---- Xbr bricks (swizzled)
    int idx = blk;
    int b = idx / 18, r0 = (idx % 18) * 8;
    __hip_bfloat16* base = Xbr + (size_t)b * (NK0 * BRICK_ROWS * 32);
    for (int r = r0; r < r0 + 8; ++r) {
      int lp = r - 3;
      int xr = (r >> 1) & 3;
      if (lp >= 0 && lp < L) {
        int tok = tokens[b * L + lp];
        int pp = pos[b * L + lp] + 100;
        const float* wrow = word_embs + (size_t)tok * WDIM;
        const float* prow = pos_emb + (size_t)pp * PDIM;
        for (int d = tid; d < 352; d += 256) {
          float v = (d < WDIM) ? wrow[d] : (d < DIM) ? prow[d - WDIM] : 0.f;
          int slot = (d >> 3) & 3;
          base[((size_t)(d >> 5) * BRICK_ROWS + r) * 32 +
               ((slot ^ xr) << 3) + (d & 7)] = __float2bfloat16(v);
        }
      } else {
        for (int d = tid; d < 352; d += 256) {
          int slot = (d >> 3) & 3;
          base[((size_t)(d >> 5) * BRICK_ROWS + r) * 32 +
               ((slot ^ xr) << 3) + (d & 7)] = __float2bfloat16(0.f);
        }
      }
    }
  } else if (blk < 1383) {  // ---- Wbr bricks
    int idx = blk - 1152;
    int ncg = idx / NKK, kkb = idx % NKK;
    if (tid < 128) {
      int k0 = kkb / NSHIFT, s = kkb - NSHIFT * k0;
      int col = tid;
      const float* w = (ncg == 0) ? w3 : (ncg == 1) ? w5 : w7;
      int fs = (ncg == 0) ? 3 : (ncg == 1) ? 5 : 7;
      int dl = (ncg == 0) ? s - 2 : (ncg == 1) ? s - 1 : s;
      bool valid = (dl >= 0 && dl < fs);
      __hip_bfloat16* dst = Wbr + (((size_t)ncg * NKK + kkb) * 128 + col) * 32;
      for (int k = 0; k < 32; ++k) {
        int d = k0 * 32 + k;
        float v =
            (valid && d < DIM) ? w[((size_t)col * fs + dl) * DIM + d] : 0.f;
        dst[k] = __float2bfloat16(v);
      }
    }
  } else {  // ---- ctxpool init (must precede conv's atomicMax)
    int idx = blk - 1383;
    int i0 = idx * 1024 + tid * 4;
#pragma unroll
    for (int q = 0; q < 4; ++q) ctxpool[i0 + q] = -NEG_INF_F;
  }
}

// ---------------------------------------------------------------------------
// K2 k_work: conv [0,768) + cand [768,2048) + W1br [2048,2304) in ONE grid —
// conv's MFMA blocks and cand's latency-bound gather blocks co-schedule on
// the same CUs. LDS sections unioned (max 14.8 KB).
__global__ __launch_bounds__(256) void k_work(
    const __hip_bfloat16* __restrict__ Xbr,
    const __hip_bfloat16* __restrict__ Wbr, const int* __restrict__ pos,
    const float* __restrict__ masks, const float* __restrict__ b3,
    const float* __restrict__ b5, const float* __restrict__ b7,
    float* __restrict__ ctxpool, const int* __restrict__ nb_types,
    const int* __restrict__ nb_n_types, const int* __restrict__ nb_rs,
    const float* __restrict__ type_emb, const float* __restrict__ rel_emb,
    const float* __restrict__ rel_weight, __hip_bfloat16* __restrict__ candb,
    const float* __restrict__ sW1, const float* __restrict__ nW1,
    __hip_bfloat16* __restrict__ W1br) {
  __shared__ __align__(16) char smem[14848];
  int blk = blockIdx.x, tid = threadIdx.x;

  if (blk < 768) {  // =============================== conv
    int idx = blk;
    int b = idx / 12;
    int rem = idx - b * 12;
    int mt = rem / 6, nt = rem - mt * 6;
    int ncg = nt >> 1, nh = nt & 1;
    int slo = 2 - ncg, shi = 4 + ncg;  // valid taps: 3 / 5 / 7
    int wv = tid >> 6, ln = tid & 63;
    int wm = wv >> 1, wn = wv & 1;
    int l15 = ln & 15, kg = ln >> 4;

    __hip_bfloat16* Asb = (__hip_bfloat16*)smem;      // 2 x 80*32 = 10240 B
    float* sml = (float*)(smem + 10240);              // 256 B
    float* smr = (float*)(smem + 10496);              // 256 B

    if (tid < 64) {
      int l = mt * 64 + tid;
      float mlv = 0.f, mrv = 0.f;
      if (l < L) {
        int p = pos[b * L + l];
        mlv = (p <= 0) ? 1.f : 0.f;
        mrv = (p >= 0) ? masks[b * L + l] : 0.f;
      }
      sml[tid] = mlv;
      smr[tid] = mrv;
    }

    const __hip_bfloat16* XB =
        Xbr + (size_t)b * (NK0 * BRICK_ROWS * 32) + (size_t)mt * 64 * 32;
    const __hip_bfloat16* WBl =
        Wbr + ((size_t)ncg * NKK * 128 + nh * 64 + wn * 32 + l15) * 32 +
        kg * 8;

    for (int seg = wv; seg < 5; seg += 4)
      gload_lds16(XB + (seg * 64 + ln) * 8, &Asb[(seg * 64 + ln) * 8]);
    __syncthreads();

    f32x4 acc[2][2];
#pragma unroll
    for (int i = 0; i < 2; ++i)
#pragma unroll
      for (int j = 0; j < 2; ++j) acc[i][j] = (f32x4){0.f, 0.f, 0.f, 0.f};

    int buf = 0;
    for (int k0 = 0; k0 < NK0; ++k0) {
      if (k0 < NK0 - 1) {
        const __hip_bfloat16* asrc = XB + (size_t)(k0 + 1) * (BRICK_ROWS * 32);
        for (int seg = wv; seg < 5; seg += 4)
          gload_lds16(asrc + (seg * 64 + ln) * 8,
                      &Asb[(buf ^ 1) * 2560 + (seg * 64 + ln) * 8]);
      }
#pragma unroll
      for (int s = 0; s < NSHIFT; ++s) {
        if (s < slo || s > shi) continue;  // block-uniform: skip zero taps
        const __hip_bfloat16* bp = WBl + (size_t)(k0 * NSHIFT + s) * 4096;
        bf16x8 bf0 = *(const bf16x8*)(bp);
        bf16x8 bf1 = *(const bf16x8*)(bp + 512);
        int rbase = wm * 32 + l15 + s;
        int xr = (kg ^ ((rbase >> 1) & 3)) << 3;
        bf16x8 af0 = *(const bf16x8*)&Asb[buf * 2560 + rbase * 32 + xr];
        bf16x8 af1 = *(const bf16x8*)&Asb[buf * 2560 + (rbase + 16) * 32 + xr];
        acc[0][0] = __builtin_amdgcn_mfma_f32_16x16x32_bf16(af0, bf0, acc[0][0], 0, 0, 0);
        acc[0][1] = __builtin_amdgcn_mfma_f32_16x16x32_bf16(af0, bf1, acc[0][1], 0, 0, 0);
        acc[1][0] = __builtin_amdgcn_mfma_f32_16x16x32_bf16(af1, bf0, acc[1][0], 0, 0, 0);
        acc[1][1] = __builtin_amdgcn_mfma_f32_16x16x32_bf16(af1, bf1, acc[1][1], 0, 0, 0);
      }
      __syncthreads();
      buf ^= 1;
    }

    const float* barr = (ncg == 0) ? b3 : (ncg == 1) ? b5 : b7;
#pragma unroll
    for (int j = 0; j < 2; ++j) {
      int fcol = nh * 64 + wn * 32 + 16 * j + l15;
      float bias = barr[fcol];
      float mpl = -NEG_INF_F, mpr = -NEG_INF_F;
#pragma unroll
      for (int i = 0; i < 2; ++i) {
#pragma unroll
        for (int r = 0; r < 4; ++r) {
          int rl = wm * 32 + 16 * i + 4 * kg + r;
          float cva = fmaxf(acc[i][j][r] + bias, 0.f);
          float ml = sml[rl], mr = smr[rl];
          mpl = fmaxf(mpl, cva * ml - (1.f - ml) * NEG_INF_F);
          mpr = fmaxf(mpr, cva * mr - (1.f - mr) * NEG_INF_F);
        }
      }
      mpl = fmaxf(mpl, __shfl_xor(mpl, 16));
      mpl = fmaxf(mpl, __shfl_xor(mpl, 32));
      mpr = fmaxf(mpr, __shfl_xor(mpr, 16));
      mpr = fmaxf(mpr, __shfl_xor(mpr, 32));
      if (ln < 16) {
        atomicMax((int*)&ctxpool[(size_t)b * CTX_DIM + ncg * 128 + fcol],
                  __float_as_int(mpl));
        atomicMax((int*)&ctxpool[(size_t)b * CTX_DIM + 384 + ncg * 128 + fcol],
                  __float_as_int(mpr));
      }
    }
  } else if (blk < 2048) {  // =============================== cand
    int c = blk - 768;
    int g = tid >> 7, d = tid & 127;
    int* sty = (int*)smem;                  // 1024 B
    int* srs = (int*)(smem + 1024);         // 256 B
    float* sinv = (float*)(smem + 1280);    // 256 B
    float* pS = (float*)(smem + 1536);      // [2][128] 1024 B
    float* pR = (float*)(smem + 2560);      // 1024 B
    float* sS = (float*)(smem + 3584);      // 512 B
    sty[tid] = nb_types[c * NB_PER_CAND * 4 + tid];
    if (tid < NB_PER_CAND) {
      srs[tid] = nb_rs[c * NB_PER_CAND + tid];
      sinv[tid] = 1.f / (float)nb_n_types[c * NB_PER_CAND + tid];
    }
    __syncthreads();
    float accS = 0.f, accR = 0.f;
#pragma unroll 4
    for (int j2 = 0; j2 < 32; ++j2) {
      int j = g * 32 + j2;
      accR += rel_emb[srs[j] * EDIM + d];
      float s4 = 0.f;
#pragma unroll
      for (int k = 0; k < 4; ++k) s4 += type_emb[sty[j * 4 + k] * TDIM + d];
      accS = fmaf(s4, sinv[j], accS);
    }
    pS[g * 128 + d] = accS;
    pR[g * 128 + d] = accR;
    __syncthreads();
    if (tid < 128) sS[d] = pS[d] + pS[128 + d];
    __syncthreads();
    float dotp = (g == 0) ? (pR[d] + pR[128 + d]) : 0.f;
#pragma unroll 4
    for (int k2 = 0; k2 < 64; ++k2) {
      int k = g * 64 + k2;
      dotp = fmaf(sS[k], rel_weight[k * EDIM + d], dotp);
    }
    pS[g * 128 + d] = dotp;
    __syncthreads();
    if (tid < 128)
      candb[(size_t)c * EDIM + d] =
          __float2bfloat16(fmaxf(pS[d] + pS[128 + d], 0.f));
  } else {  // =============================== W1br tile transpose
    int idx = blk - 2048;            // 0..255
    int which = idx >> 7;            // 0..1
    int rem = idx & 127;
    int sub = rem >> 3;              // 0..15
    int kc = rem & 7;                // 0..7 (112 k each)
    float* tile = (float*)smem;      // [112][33] = 14784 B
    const float* src = which ? nW1 : sW1;
    __hip_bfloat16* dst = W1br + (size_t)which * (16 * 56 * 512);
    for (int i = tid; i < 112 * 32; i += 256) {
      int kk = i >> 5, col = i & 31;
      tile[kk * 33 + col] =
          src[(size_t)(kc * 112 + kk) * EN_DIM + sub * 32 + col];
    }
    __syncthreads();
    for (int i = tid; i < 32 * 112; i += 256) {
      int col = i / 112, kk = i - col * 112;
      int k = kc * 112 + kk;
      dst[((size_t)(sub * 56 + (k >> 4)) * 32 + col) * 16 + (k & 15)] =
          __float2bfloat16(tile[kk * 33 + col]);
    }
  }
}

// ---------------------------------------------------------------------------
// K3: scorer GEMM (mt<40) + noise ctx-part (mt 40..41 -> hctxn).
// Grid (42, 8) x 128 threads. As staged with 16B-slot XOR swizzle.
__global__ __launch_bounds__(128) void k_mlp(
    const float* __restrict__ ctxp, const __hip_bfloat16* __restrict__ candb,
    const __hip_bfloat16* __restrict__ W1br, const float* __restrict__ sb1,
    const float* __restrict__ sW2, float* __restrict__ part,
    float* __restrict__ hctxn) {
  int mt = blockIdx.x;
  bool noise = (mt >= 40);
  int w = threadIdx.x >> 6;
  int sub = blockIdx.y * 2 + w;
  int lane = threadIdx.x & 63;
  int lrow = lane & 31, kg2 = lane >> 5;
  __shared__ __align__(16) __hip_bfloat16 As[32 * 904];

  {
    int row = threadIdx.x >> 2, seg = threadIdx.x & 3;
    int xr = (row >> 1) & 7;
    if (!noise) {
      int m = mt * 32 + row;
      int bb = m / 20;
      const float* cp = ctxp + (size_t)bb * CTX_DIM;
#pragma unroll
      for (int q = 0; q < 28; ++q) {
        int k = seg * 224 + q * 8;
        bf16x8 v;
        if (k < CTX_DIM)
          v = cvt8(*(const float4*)(cp + k), *(const float4*)(cp + k + 4));
        else
          v = *(const bf16x8*)&candb[(size_t)m * EDIM + (k - CTX_DIM)];
        *(bf16x8*)&As[row * 904 + (((k >> 3) ^ xr) << 3)] = v;
      }
    } else {
      int bb = (mt - 40) * 32 + row;
      const float* cp = ctxp + (size_t)bb * CTX_DIM;
#pragma unroll
      for (int q = 0; q < 28; ++q) {
        int k = seg * 224 + q * 8;
        if (k < CTX_DIM)
          *(bf16x8*)&As[row * 904 + (((k >> 3) ^ xr) << 3)] =
              cvt8(*(const float4*)(cp + k), *(const float4*)(cp + k + 4));
      }
    }
  }
  __syncthreads();

  int xrr = (lrow >> 1) & 7;
  f32x16 acc = {};
  if (!noise) {
    const __hip_bfloat16* W1b = W1br;
#pragma unroll 4
    for (int k0 = 0; k0 < 56; ++k0) {
      int s16 = k0 * 2 + kg2;
      bf16x8 av = *(const bf16x8*)&As[lrow * 904 + ((s16 ^ xrr) << 3)];
      bf16x8 bv = *(const bf16x8*)&W1b[((size_t)sub * 56 + k0) * 512 +
                                       lrow * 16 + kg2 * 8];
      acc = __builtin_amdgcn_mfma_f32_32x32x16_bf16(av, bv, acc, 0, 0, 0);
    }
    int n = sub * 32 + lrow;
    float b1n = sb1[n], w2n = sW2[n];
#pragma unroll
    for (int r = 0; r < 16; ++r) {
      float v = fmaxf(acc[r] + b1n, 0.f) * w2n;
#pragma unroll
      for (int off = 16; off; off >>= 1) v += __shfl_xor(v, off);
      if (lrow == 0) {
        int mm = mt * 32 + (r & 3) + 8 * (r >> 2) + 4 * kg2;
        part[(size_t)sub * (B * N_CANDS) + mm] = v;
      }
    }
  } else {
    const __hip_bfloat16* W1b = W1br + (size_t)(16 * 56 * 512);
#pragma unroll 4
    for (int k0 = 0; k0 < 48; ++k0) {
      int s16 = k0 * 2 + kg2;
      bf16x8 av = *(const bf16x8*)&As[lrow * 904 + ((s16 ^ xrr) << 3)];
      bf16x8 bv = *(const bf16x8*)&W1b[((size_t)sub * 56 + k0) * 512 +
                                       lrow * 16 + kg2 * 8];
      acc = __builtin_amdgcn_mfma_f32_32x32x16_bf16(av, bv, acc, 0, 0, 0);
    }
#pragma unroll
    for (int r = 0; r < 16; ++r) {
      int mrow = (r & 3) + 8 * (r >> 2) + 4 * kg2;
      hctxn[(size_t)((mt - 40) * 32 + mrow) * EN_DIM + sub * 32 + lrow] =
          acc[r];
    }
  }
}

// ---------------------------------------------------------------------------
// K4 tail: one block per batch row (64 x 256). Scores finish+write,
// softmax(10), e (f32), vector noise head on f32 nW1 rows 768..895.
__global__ __launch_bounds__(256) void k_tail(
    const float* __restrict__ part, const __hip_bfloat16* __restrict__ candb,
    const float* __restrict__ hctxn, const int* __restrict__ real_n_poss,
    const float* __restrict__ sb2, const float* __restrict__ nW1,
    const float* __restrict__ nb1, const float* __restrict__ nW2,
    const float* __restrict__ nb2, float* __restrict__ out) {
  int b = blockIdx.x, tid = threadIdx.x;
  __shared__ float ssc[N_CANDS];
  __shared__ float sp[N_POSS];
  __shared__ float e_sh[EDIM];
  __shared__ float red[4];

  if (tid < N_CANDS) {
    int m = b * N_CANDS + tid;
    float s = sb2[0];
#pragma unroll
    for (int p = 0; p < 16; ++p) s += part[(size_t)p * (B * N_CANDS) + m];
    if (tid < N_POSS && (tid + 1) > real_n_poss[b]) s = -NEG_INF_F;
    ssc[tid] = s;
    out[m] = s;
  }
  __syncthreads();
  if (tid == 0) {
    float mx = -INFINITY;
#pragma unroll
    for (int c = 0; c < N_POSS; ++c) mx = fmaxf(mx, ssc[c]);
    float ssum = 0.f;
    float pe[N_POSS];
#pragma unroll
    for (int c = 0; c < N_POSS; ++c) {
      pe[c] = expf(ssc[c] - mx);
      ssum += pe[c];
    }
    float inv = 1.f / ssum;
#pragma unroll
    for (int c = 0; c < N_POSS; ++c) sp[c] = pe[c] * inv;
  }
  __syncthreads();
  if (tid < EDIM) {
    float ev = 0.f;
#pragma unroll
    for (int c = 0; c < N_POSS; ++c)
      ev = fmaf(sp[c],
                __bfloat162float(candb[(size_t)(b * N_CANDS + c) * EDIM + tid]),
                ev);
    e_sh[tid] = ev;
  }
  __syncthreads();

  float h0 = nb1[tid] + hctxn[(size_t)b * EN_DIM + tid];
  float h1 = nb1[tid + 256] + hctxn[(size_t)b * EN_DIM + tid + 256];
#pragma unroll 4
  for (int k = 0; k < EDIM; ++k) {
    float ek = e_sh[k];
    const float* wr = nW1 + (size_t)(CTX_DIM + k) * EN_DIM;
    h0 = fmaf(ek, wr[tid], h0);
    h1 = fmaf(ek, wr[tid + 256], h1);
  }
  float v = fmaxf(h0, 0.f) * nW2[tid] + fmaxf(h1, 0.f) * nW2[tid + 256];
#pragma unroll
  for (int off = 32; off; off >>= 1) v += __shfl_xor(v, off);
  if ((tid & 63) == 0) red[tid >> 6] = v;
  __syncthreads();
  if (tid == 0)
    out[B * N_CANDS + b] = red[0] + red[1] + red[2] + red[3] + nb2[0];
}

// ---------------------------------------------------------------------------
extern "C" void kernel_launch(void* const* d_in, const int* in_sizes, int n_in,
                              void* d_out, int out_size, void* d_ws,
                              size_t ws_size, hipStream_t stream) {
  const int* tokens = (const int*)d_in[0];
  const int* pos = (const int*)d_in[1];
  const float* masks = (const float*)d_in[2];
  const int* nb_types = (const int*)d_in[3];
  const int* nb_n_types = (const int*)d_in[5];
  const int* nb_rs = (const int*)d_in[6];
  const int* real_n_poss = (const int*)d_in[8];
  const float* word_embs = (const float*)d_in[10];
  const float* pos_emb = (const float*)d_in[11];
  const float* type_emb = (const float*)d_in[12];
  const float* rel_emb = (const float*)d_in[13];
  const float* rel_weight = (const float*)d_in[14];
  const float* w3 = (const float*)d_in[15];
  const float* b3 = (const float*)d_in[16];
  const float* w5 = (const float*)d_in[17];
  const float* b5 = (const float*)d_in[18];
  const float* w7 = (const float*)d_in[19];
  const float* b7 = (const float*)d_in[20];
  const float* sW1 = (const float*)d_in[21];
  const float* sb1 = (const float*)d_in[22];
  const float* sW2 = (const float*)d_in[23];
  const float* sb2 = (const float*)d_in[24];
  const float* nW1 = (const float*)d_in[25];
  const float* nb1 = (const float*)d_in[26];
  const float* nW2 = (const float*)d_in[27];
  const float* nb2 = (const float*)d_in[28];

  __hip_bfloat16* Xbr = (__hip_bfloat16*)d_ws;          // 3,244,032 bf16
  __hip_bfloat16* Wbr = Xbr + (size_t)3244032;          //   946,176
  __hip_bfloat16* W1br = Wbr + (size_t)946176;          //   917,504
  __hip_bfloat16* candb = W1br + (size_t)917504;        //   163,840
  float* ctxpool = (float*)(candb + (size_t)163840);    //    49,152 f32
  float* part = ctxpool + (size_t)B * CTX_DIM;          //    20,480 f32
  float* hctxn = part + (size_t)16 * B * N_CANDS;       //    32,768 f32
  float* out = (float*)d_out;

  hipLaunchKernelGGL(k_front, dim3(1431), dim3(256), 0, stream, tokens, pos,
                     word_embs, pos_emb, Xbr, w3, w5, w7, Wbr, ctxpool);
  hipLaunchKernelGGL(k_work, dim3(2304), dim3(256), 0, stream, Xbr, Wbr, pos,
                     masks, b3, b5, b7, ctxpool, nb_types, nb_n_types, nb_rs,
                     type_emb, rel_emb, rel_weight, candb, sW1, nW1, W1br);
  hipLaunchKernelGGL(k_mlp, dim3(42, 8), dim3(128), 0, stream, ctxpool, candb,
                     W1br, sb1, sW2, part, hctxn);
  hipLaunchKernelGGL(k_tail, dim3(B), dim3(256), 0, stream, part, candb,
                     hctxn, real_n_poss, sb2, nW1, nb1, nW2, nb2, out);
}

// Round 10
// 83.719 us; speedup vs baseline: 1.8462x; 1.0082x over previous
//
#include <hip/hip_runtime.h>
#include <hip/hip_bf16.h>

#define B 64
#define L 100
#define WDIM 300
#define PDIM 50
#define DIM 350
#define NK0 11              // 352/32 k-chunks
#define BRICK_ROWS 144      // rows per (b,k0) brick; row r -> l' = r-3
#define NSHIFT 7
#define NKK 77              // 11 k0 * 7 shifts
#define N_CANDS 20
#define N_POSS 10
#define NB_PER_CAND 64
#define TDIM 128
#define EDIM 128
#define CTX_DIM 768
#define EN_HID1 896
#define EN_DIM 512
#define NEG_INF_F 1.0e10f

typedef __attribute__((ext_vector_type(8))) short bf16x8;
typedef __attribute__((ext_vector_type(4))) float f32x4;
typedef __attribute__((ext_vector_type(16))) float f32x16;

__device__ __forceinline__ void gload_lds16(const __hip_bfloat16* g,
                                            __hip_bfloat16* l) {
  __builtin_amdgcn_global_load_lds(
      (const __attribute__((address_space(1))) unsigned int*)(g),
      (__attribute__((address_space(3))) unsigned int*)(l), 16, 0, 0);
}

__device__ __forceinline__ bf16x8 cvt8(float4 a, float4 b) {
  union { bf16x8 v; __hip_bfloat16 h[8]; } u;
  u.h[0] = __float2bfloat16(a.x); u.h[1] = __float2bfloat16(a.y);
  u.h[2] = __float2bfloat16(a.z); u.h[3] = __float2bfloat16(a.w);
  u.h[4] = __float2bfloat16(b.x); u.h[5] = __float2bfloat16(b.y);
  u.h[6] = __float2bfloat16(b.z); u.h[7] = __float2bfloat16(b.w);
  return u.v;
}

// ---------------------------------------------------------------------------
// K1 k_front: conv prerequisites + table casts.
// [0,1152) Xbr (pre-swizzled); [1152,1383) Wbr; [1383,1431) ctxpool init;
// [1431,2135) cast type/rel/relw tables f32 -> bf16 (for cand in k_work).
__global__ __launch_bounds__(256) void k_front(
    const int* __restrict__ tokens, const int* __restrict__ pos,
    const float* __restrict__ word_embs, const float* __restrict__ pos_emb,
    __hip_bfloat16* __restrict__ Xbr, const float* __restrict__ w3,
    const float* __restrict__ w5, const float* __restrict__ w7,
    __hip_bfloat16* __restrict__ Wbr, float* __restrict__ ctxpool,
    const float* __restrict__ type_emb, const float* __restrict__ rel_emb,
    const float* __restrict__ rel_weight, __hip_bfloat16* __restrict__ typeb,
    __hip_bfloat16* __restrict__ relb, __hip_bfloat16* __restrict__ relwb) {
  int blk = blockIdx.x, tid = threadIdx.x;
  if (blk < 1152) {  // ---- Xbr bricks (swizzled)
    int idx = blk;
    int b = idx / 18, r0 = (idx % 18) * 8;
    __hip_bfloat16* base = Xbr + (size_t)b * (NK0 * BRICK_ROWS * 32);
    for (int r = r0; r < r0 + 8; ++r) {
      int lp = r - 3;
      int xr = (r >> 1) & 3;
      if (lp >= 0 && lp < L) {
        int tok = tokens[b * L + lp];
        int pp = pos[b * L + lp] + 100;
        const float* wrow = word_embs + (size_t)tok * WDIM;
        const float* prow = pos_emb + (size_t)pp * PDIM;
        for (int d = tid; d < 352; d += 256) {
          float v = (d < WDIM) ? wrow[d] : (d < DIM) ? prow[d - WDIM] : 0.f;
          int slot = (d >> 3) & 3;
          base[((size_t)(d >> 5) * BRICK_ROWS + r) * 32 +
               ((slot ^ xr) << 3) + (d & 7)] = __float2bfloat16(v);
        }
      } else {
        for (int d = tid; d < 352; d += 256) {
          int slot = (d >> 3) & 3;
          base[((size_t)(d >> 5) * BRICK_ROWS + r) * 32 +
               ((slot ^ xr) << 3) + (d & 7)] = __float2bfloat16(0.f);
        }
      }
    }
  } else if (blk < 1383) {  // ---- Wbr bricks
    int idx = blk - 1152;
    int ncg = idx / NKK, kkb = idx % NKK;
    if (tid < 128) {
      int k0 = kkb / NSHIFT, s = kkb - NSHIFT * k0;
      int col = tid;
      const float* w = (ncg == 0) ? w3 : (ncg == 1) ? w5 : w7;
      int fs = (ncg == 0) ? 3 : (ncg == 1) ? 5 : 7;
      int dl = (ncg == 0) ? s - 2 : (ncg == 1) ? s - 1 : s;
      bool valid = (dl >= 0 && dl < fs);
      __hip_bfloat16* dst = Wbr + (((size_t)ncg * NKK + kkb) * 128 + col) * 32;
      for (int k = 0; k < 32; ++k) {
        int d = k0 * 32 + k;
        float v =
            (valid && d < DIM) ? w[((size_t)col * fs + dl) * DIM + d] : 0.f;
        dst[k] = __float2bfloat16(v);
      }
    }
  } else if (blk < 1431) {  // ---- ctxpool init (must precede conv atomicMax)
    int idx = blk - 1383;
    int i0 = idx * 1024 + tid * 4;
#pragma unroll
    for (int q = 0; q < 4; ++q) ctxpool[i0 + q] = -NEG_INF_F;
  } else {  // ---- table casts f32 -> bf16
    const int n1 = 5000 * TDIM, n2 = 500 * EDIM, n3 = TDIM * EDIM;
    int i0 = (blk - 1431) * 1024 + tid;
#pragma unroll
    for (int q = 0; q < 4; ++q) {
      int i = i0 + q * 256;
      if (i < n1) typeb[i] = __float2bfloat16(type_emb[i]);
      else if (i < n1 + n2) relb[i - n1] = __float2bfloat16(rel_emb[i - n1]);
      else if (i < n1 + n2 + n3)
        relwb[i - n1 - n2] = __float2bfloat16(rel_weight[i - n1 - n2]);
    }
  }
}

// ---------------------------------------------------------------------------
// K2 k_work: conv [0,768) + cand [768,2048) (bf16 tables: half the L2 gather
// traffic) + W1br [2048,2304) in ONE grid — MFMA blocks and latency-bound
// gather blocks co-schedule on the same CUs. LDS unioned (max 14.8 KB).
__global__ __launch_bounds__(256) void k_work(
    const __hip_bfloat16* __restrict__ Xbr,
    const __hip_bfloat16* __restrict__ Wbr, const int* __restrict__ pos,
    const float* __restrict__ masks, const float* __restrict__ b3,
    const float* __restrict__ b5, const float* __restrict__ b7,
    float* __restrict__ ctxpool, const int* __restrict__ nb_types,
    const int* __restrict__ nb_n_types, const int* __restrict__ nb_rs,
    const __hip_bfloat16* __restrict__ typeb,
    const __hip_bfloat16* __restrict__ relb,
    const __hip_bfloat16* __restrict__ relwb,
    __hip_bfloat16* __restrict__ candb, const float* __restrict__ sW1,
    const float* __restrict__ nW1, __hip_bfloat16* __restrict__ W1br) {
  __shared__ __align__(16) char smem[14848];
  int blk = blockIdx.x, tid = threadIdx.x;

  if (blk < 768) {  // =============================== conv
    int idx = blk;
    int b = idx / 12;
    int rem = idx - b * 12;
    int mt = rem / 6, nt = rem - mt * 6;
    int ncg = nt >> 1, nh = nt & 1;
    int slo = 2 - ncg, shi = 4 + ncg;  // valid taps: 3 / 5 / 7
    int wv = tid >> 6, ln = tid & 63;
    int wm = wv >> 1, wn = wv & 1;
    int l15 = ln & 15, kg = ln >> 4;

    __hip_bfloat16* Asb = (__hip_bfloat16*)smem;      // 2 x 80*32 = 10240 B
    float* sml = (float*)(smem + 10240);              // 256 B
    float* smr = (float*)(smem + 10496);              // 256 B

    if (tid < 64) {
      int l = mt * 64 + tid;
      float mlv = 0.f, mrv = 0.f;
      if (l < L) {
        int p = pos[b * L + l];
        mlv = (p <= 0) ? 1.f : 0.f;
        mrv = (p >= 0) ? masks[b * L + l] : 0.f;
      }
      sml[tid] = mlv;
      smr[tid] = mrv;
    }

    const __hip_bfloat16* XB =
        Xbr + (size_t)b * (NK0 * BRICK_ROWS * 32) + (size_t)mt * 64 * 32;
    const __hip_bfloat16* WBl =
        Wbr + ((size_t)ncg * NKK * 128 + nh * 64 + wn * 32 + l15) * 32 +
        kg * 8;

    for (int seg = wv; seg < 5; seg += 4)
      gload_lds16(XB + (seg * 64 + ln) * 8, &Asb[(seg * 64 + ln) * 8]);
    __syncthreads();

    f32x4 acc[2][2];
#pragma unroll
    for (int i = 0; i < 2; ++i)
#pragma unroll
      for (int j = 0; j < 2; ++j) acc[i][j] = (f32x4){0.f, 0.f, 0.f, 0.f};

    int buf = 0;
    for (int k0 = 0; k0 < NK0; ++k0) {
      if (k0 < NK0 - 1) {
        const __hip_bfloat16* asrc = XB + (size_t)(k0 + 1) * (BRICK_ROWS * 32);
        for (int seg = wv; seg < 5; seg += 4)
          gload_lds16(asrc + (seg * 64 + ln) * 8,
                      &Asb[(buf ^ 1) * 2560 + (seg * 64 + ln) * 8]);
      }
#pragma unroll
      for (int s = 0; s < NSHIFT; ++s) {
        if (s < slo || s > shi) continue;  // block-uniform: skip zero taps
        const __hip_bfloat16* bp = WBl + (size_t)(k0 * NSHIFT + s) * 4096;
        bf16x8 bf0 = *(const bf16x8*)(bp);
        bf16x8 bf1 = *(const bf16x8*)(bp + 512);
        int rbase = wm * 32 + l15 + s;
        int xr = (kg ^ ((rbase >> 1) & 3)) << 3;
        bf16x8 af0 = *(const bf16x8*)&Asb[buf * 2560 + rbase * 32 + xr];
        bf16x8 af1 = *(const bf16x8*)&Asb[buf * 2560 + (rbase + 16) * 32 + xr];
        acc[0][0] = __builtin_amdgcn_mfma_f32_16x16x32_bf16(af0, bf0, acc[0][0], 0, 0, 0);
        acc[0][1] = __builtin_amdgcn_mfma_f32_16x16x32_bf16(af0, bf1, acc[0][1], 0, 0, 0);
        acc[1][0] = __builtin_amdgcn_mfma_f32_16x16x32_bf16(af1, bf0, acc[1][0], 0, 0, 0);
        acc[1][1] = __builtin_amdgcn_mfma_f32_16x16x32_bf16(af1, bf1, acc[1][1], 0, 0, 0);
      }
      __syncthreads();
      buf ^= 1;
    }

    const float* barr = (ncg == 0) ? b3 : (ncg == 1) ? b5 : b7;
#pragma unroll
    for (int j = 0; j < 2; ++j) {
      int fcol = nh * 64 + wn * 32 + 16 * j + l15;
      float bias = barr[fcol];
      float mpl = -NEG_INF_F, mpr = -NEG_INF_F;
#pragma unroll
      for (int i = 0; i < 2; ++i) {
#pragma unroll
        for (int r = 0; r < 4; ++r) {
          int rl = wm * 32 + 16 * i + 4 * kg + r;
          float cva = fmaxf(acc[i][j][r] + bias, 0.f);
          float ml = sml[rl], mr = smr[rl];
          mpl = fmaxf(mpl, cva * ml - (1.f - ml) * NEG_INF_F);
          mpr = fmaxf(mpr, cva * mr - (1.f - mr) * NEG_INF_F);
        }
      }
      mpl = fmaxf(mpl, __shfl_xor(mpl, 16));
      mpl = fmaxf(mpl, __shfl_xor(mpl, 32));
      mpr = fmaxf(mpr, __shfl_xor(mpr, 16));
      mpr = fmaxf(mpr, __shfl_xor(mpr, 32));
      if (ln < 16) {
        atomicMax((int*)&ctxpool[(size_t)b * CTX_DIM + ncg * 128 + fcol],
                  __float_as_int(mpl));
        atomicMax((int*)&ctxpool[(size_t)b * CTX_DIM + 384 + ncg * 128 + fcol],
                  __float_as_int(mpr));
      }
    }
  } else if (blk < 2048) {  // =============================== cand (bf16)
    int c = blk - 768;
    int g = tid >> 7, d = tid & 127;
    int* sty = (int*)smem;                  // 1024 B
    int* srs = (int*)(smem + 1024);         // 256 B
    float* sinv = (float*)(smem + 1280);    // 256 B
    float* pS = (float*)(smem + 1536);      // [2][128] 1024 B
    float* pR = (float*)(smem + 2560);      // 1024 B
    float* sS = (float*)(smem + 3584);      // 512 B
    sty[tid] = nb_types[c * NB_PER_CAND * 4 + tid];
    if (tid < NB_PER_CAND) {
      srs[tid] = nb_rs[c * NB_PER_CAND + tid];
      sinv[tid] = 1.f / (float)nb_n_types[c * NB_PER_CAND + tid];
    }
    __syncthreads();
    float accS = 0.f, accR = 0.f;
#pragma unroll 4
    for (int j2 = 0; j2 < 32; ++j2) {
      int j = g * 32 + j2;
      accR += __bfloat162float(relb[srs[j] * EDIM + d]);
      float s4 = 0.f;
#pragma unroll
      for (int k = 0; k < 4; ++k)
        s4 += __bfloat162float(typeb[sty[j * 4 + k] * TDIM + d]);
      accS = fmaf(s4, sinv[j], accS);
    }
    pS[g * 128 + d] = accS;
    pR[g * 128 + d] = accR;
    __syncthreads();
    if (tid < 128) sS[d] = pS[d] + pS[128 + d];
    __syncthreads();
    float dotp = (g == 0) ? (pR[d] + pR[128 + d]) : 0.f;
#pragma unroll 4
    for (int k2 = 0; k2 < 64; ++k2) {
      int k = g * 64 + k2;
      dotp = fmaf(sS[k], __bfloat162float(relwb[k * EDIM + d]), dotp);
    }
    pS[g * 128 + d] = dotp;
    __syncthreads();
    if (tid < 128)
      candb[(size_t)c * EDIM + d] =
          __float2bfloat16(fmaxf(pS[d] + pS[128 + d], 0.f));
  } else {  // =============================== W1br tile transpose
    int idx = blk - 2048;            // 0..255
    int which = idx >> 7;            // 0..1
    int rem = idx & 127;
    int sub = rem >> 3;              // 0..15
    int kc = rem & 7;                // 0..7 (112 k each)
    float* tile = (float*)smem;      // [112][33] = 14784 B
    const float* src = which ? nW1 : sW1;
    __hip_bfloat16* dst = W1br + (size_t)which * (16 * 56 * 512);
    for (int i = tid; i < 112 * 32; i += 256) {
      int kk = i >> 5, col = i & 31;
      tile[kk * 33 + col] =
          src[(size_t)(kc * 112 + kk) * EN_DIM + sub * 32 + col];
    }
    __syncthreads();
    for (int i = tid; i < 32 * 112; i += 256) {
      int col = i / 112, kk = i - col * 112;
      int k = kc * 112 + kk;
      dst[((size_t)(sub * 56 + (k >> 4)) * 32 + col) * 16 + (k & 15)] =
          __float2bfloat16(tile[kk * 33 + col]);
    }
  }
}

// ---------------------------------------------------------------------------
// K3: scorer GEMM (mt<40) + noise ctx-part (mt 40..41 -> hctxn).
// Grid (42, 8) x 128 threads. As staged with 16B-slot XOR swizzle.
__global__ __launch_bounds__(128) void k_mlp(
    const float* __restrict__ ctxp, const __hip_bfloat16* __restrict__ candb,
    const __hip_bfloat16* __restrict__ W1br, const float* __restrict__ sb1,
    const float* __restrict__ sW2, float* __restrict__ part,
    float* __restrict__ hctxn) {
  int mt = blockIdx.x;
  bool noise = (mt >= 40);
  int w = threadIdx.x >> 6;
  int sub = blockIdx.y * 2 + w;
  int lane = threadIdx.x & 63;
  int lrow = lane & 31, kg2 = lane >> 5;
  __shared__ __align__(16) __hip_bfloat16 As[32 * 904];

  {
    int row = threadIdx.x >> 2, seg = threadIdx.x & 3;
    int xr = (row >> 1) & 7;
    if (!noise) {
      int m = mt * 32 + row;
      int bb = m / 20;
      const float* cp = ctxp + (size_t)bb * CTX_DIM;
#pragma unroll
      for (int q = 0; q < 28; ++q) {
        int k = seg * 224 + q * 8;
        bf16x8 v;
        if (k < CTX_DIM)
          v = cvt8(*(const float4*)(cp + k), *(const float4*)(cp + k + 4));
        else
          v = *(const bf16x8*)&candb[(size_t)m * EDIM + (k - CTX_DIM)];
        *(bf16x8*)&As[row * 904 + (((k >> 3) ^ xr) << 3)] = v;
      }
    } else {
      int bb = (mt - 40) * 32 + row;
      const float* cp = ctxp + (size_t)bb * CTX_DIM;
#pragma unroll
      for (int q = 0; q < 28; ++q) {
        int k = seg * 224 + q * 8;
        if (k < CTX_DIM)
          *(bf16x8*)&As[row * 904 + (((k >> 3) ^ xr) << 3)] =
              cvt8(*(const float4*)(cp + k), *(const float4*)(cp + k + 4));
      }
    }
  }
  __syncthreads();

  int xrr = (lrow >> 1) & 7;
  f32x16 acc = {};
  if (!noise) {
    const __hip_bfloat16* W1b = W1br;
#pragma unroll 4
    for (int k0 = 0; k0 < 56; ++k0) {
      int s16 = k0 * 2 + kg2;
      bf16x8 av = *(const bf16x8*)&As[lrow * 904 + ((s16 ^ xrr) << 3)];
      bf16x8 bv = *(const bf16x8*)&W1b[((size_t)sub * 56 + k0) * 512 +
                                       lrow * 16 + kg2 * 8];
      acc = __builtin_amdgcn_mfma_f32_32x32x16_bf16(av, bv, acc, 0, 0, 0);
    }
    int n = sub * 32 + lrow;
    float b1n = sb1[n], w2n = sW2[n];
#pragma unroll
    for (int r = 0; r < 16; ++r) {
      float v = fmaxf(acc[r] + b1n, 0.f) * w2n;
#pragma unroll
      for (int off = 16; off; off >>= 1) v += __shfl_xor(v, off);
      if (lrow == 0) {
        int mm = mt * 32 + (r & 3) + 8 * (r >> 2) + 4 * kg2;
        part[(size_t)sub * (B * N_CANDS) + mm] = v;
      }
    }
  } else {
    const __hip_bfloat16* W1b = W1br + (size_t)(16 * 56 * 512);
#pragma unroll 4
    for (int k0 = 0; k0 < 48; ++k0) {
      int s16 = k0 * 2 + kg2;
      bf16x8 av = *(const bf16x8*)&As[lrow * 904 + ((s16 ^ xrr) << 3)];
      bf16x8 bv = *(const bf16x8*)&W1b[((size_t)sub * 56 + k0) * 512 +
                                       lrow * 16 + kg2 * 8];
      acc = __builtin_amdgcn_mfma_f32_32x32x16_bf16(av, bv, acc, 0, 0, 0);
    }
#pragma unroll
    for (int r = 0; r < 16; ++r) {
      int mrow = (r & 3) + 8 * (r >> 2) + 4 * kg2;
      hctxn[(size_t)((mt - 40) * 32 + mrow) * EN_DIM + sub * 32 + lrow] =
          acc[r];
    }
  }
}

// ---------------------------------------------------------------------------
// K4 tail: one block per batch row (64 x 256). Scores finish+write,
// softmax(10), e (f32), vector noise head on f32 nW1 rows 768..895.
__global__ __launch_bounds__(256) void k_tail(
    const float* __restrict__ part, const __hip_bfloat16* __restrict__ candb,
    const float* __restrict__ hctxn, const int* __restrict__ real_n_poss,
    const float* __restrict__ sb2, const float* __restrict__ nW1,
    const float* __restrict__ nb1, const float* __restrict__ nW2,
    const float* __restrict__ nb2, float* __restrict__ out) {
  int b = blockIdx.x, tid = threadIdx.x;
  __shared__ float ssc[N_CANDS];
  __shared__ float sp[N_POSS];
  __shared__ float e_sh[EDIM];
  __shared__ float red[4];

  if (tid < N_CANDS) {
    int m = b * N_CANDS + tid;
    float s = sb2[0];
#pragma unroll
    for (int p = 0; p < 16; ++p) s += part[(size_t)p * (B * N_CANDS) + m];
    if (tid < N_POSS && (tid + 1) > real_n_poss[b]) s = -NEG_INF_F;
    ssc[tid] = s;
    out[m] = s;
  }
  __syncthreads();
  if (tid == 0) {
    float mx = -INFINITY;
#pragma unroll
    for (int c = 0; c < N_POSS; ++c) mx = fmaxf(mx, ssc[c]);
    float ssum = 0.f;
    float pe[N_POSS];
#pragma unroll
    for (int c = 0; c < N_POSS; ++c) {
      pe[c] = expf(ssc[c] - mx);
      ssum += pe[c];
    }
    float inv = 1.f / ssum;
#pragma unroll
    for (int c = 0; c < N_POSS; ++c) sp[c] = pe[c] * inv;
  }
  __syncthreads();
  if (tid < EDIM) {
    float ev = 0.f;
#pragma unroll
    for (int c = 0; c < N_POSS; ++c)
      ev = fmaf(sp[c],
                __bfloat162float(candb[(size_t)(b * N_CANDS + c) * EDIM + tid]),
                ev);
    e_sh[tid] = ev;
  }
  __syncthreads();

  float h0 = nb1[tid] + hctxn[(size_t)b * EN_DIM + tid];
  float h1 = nb1[tid + 256] + hctxn[(size_t)b * EN_DIM + tid + 256];
#pragma unroll 4
  for (int k = 0; k < EDIM; ++k) {
    float ek = e_sh[k];
    const float* wr = nW1 + (size_t)(CTX_DIM + k) * EN_DIM;
    h0 = fmaf(ek, wr[tid], h0);
    h1 = fmaf(ek, wr[tid + 256], h1);
  }
  float v = fmaxf(h0, 0.f) * nW2[tid] + fmaxf(h1, 0.f) * nW2[tid + 256];
#pragma unroll
  for (int off = 32; off; off >>= 1) v += __shfl_xor(v, off);
  if ((tid & 63) == 0) red[tid >> 6] = v;
  __syncthreads();
  if (tid == 0)
    out[B * N_CANDS + b] = red[0] + red[1] + red[2] + red[3] + nb2[0];
}

// ---------------------------------------------------------------------------
extern "C" void kernel_launch(void* const* d_in, const int* in_sizes, int n_in,
                              void* d_out, int out_size, void* d_ws,
                              size_t ws_size, hipStream_t stream) {
  const int* tokens = (const int*)d_in[0];
  const int* pos = (const int*)d_in[1];
  const float* masks = (const float*)d_in[2];
  const int* nb_types = (const int*)d_in[3];
  const int* nb_n_types = (const int*)d_in[5];
  const int* nb_rs = (const int*)d_in[6];
  const int* real_n_poss = (const int*)d_in[8];
  const float* word_embs = (const float*)d_in[10];
  const float* pos_emb = (const float*)d_in[11];
  const float* type_emb = (const float*)d_in[12];
  const float* rel_emb = (const float*)d_in[13];
  const float* rel_weight = (const float*)d_in[14];
  const float* w3 = (const float*)d_in[15];
  const float* b3 = (const float*)d_in[16];
  const float* w5 = (const float*)d_in[17];
  const float* b5 = (const float*)d_in[18];
  const float* w7 = (const float*)d_in[19];
  const float* b7 = (const float*)d_in[20];
  const float* sW1 = (const float*)d_in[21];
  const float* sb1 = (const float*)d_in[22];
  const float* sW2 = (const float*)d_in[23];
  const float* sb2 = (const float*)d_in[24];
  const float* nW1 = (const float*)d_in[25];
  const float* nb1 = (const float*)d_in[26];
  const float* nW2 = (const float*)d_in[27];
  const float* nb2 = (const float*)d_in[28];

  __hip_bfloat16* Xbr = (__hip_bfloat16*)d_ws;          // 3,244,032 bf16
  __hip_bfloat16* Wbr = Xbr + (size_t)3244032;          //   946,176
  __hip_bfloat16* W1br = Wbr + (size_t)946176;          //   917,504
  __hip_bfloat16* candb = W1br + (size_t)917504;        //   163,840
  __hip_bfloat16* typeb = candb + (size_t)163840;       //   640,000
  __hip_bfloat16* relb = typeb + (size_t)640000;        //    64,000
  __hip_bfloat16* relwb = relb + (size_t)64000;         //    16,384
  float* ctxpool = (float*)(relwb + (size_t)16384);     //    49,152 f32
  float* part = ctxpool + (size_t)B * CTX_DIM;          //    20,480 f32
  float* hctxn = part + (size_t)16 * B * N_CANDS;       //    32,768 f32
  float* out = (float*)d_out;

  hipLaunchKernelGGL(k_front, dim3(2135), dim3(256), 0, stream, tokens, pos,
                     word_embs, pos_emb, Xbr, w3, w5, w7, Wbr, ctxpool,
                     type_emb, rel_emb, rel_weight, typeb, relb, relwb);
  hipLaunchKernelGGL(k_work, dim3(2304), dim3(256), 0, stream, Xbr, Wbr, pos,
                     masks, b3, b5, b7, ctxpool, nb_types, nb_n_types, nb_rs,
                     typeb, relb, relwb, candb, sW1, nW1, W1br);
  hipLaunchKernelGGL(k_mlp, dim3(42, 8), dim3(128), 0, stream, ctxpool, candb,
                     W1br, sb1, sW2, part, hctxn);
  hipLaunchKernelGGL(k_tail, dim3(B), dim3(256), 0, stream, part, candb,
                     hctxn, real_n_poss, sb2, nW1, nb1, nW2, nb2, out);
}